// Round 8
// baseline (763.041 us; speedup 1.0000x reference)
//
#include <hip/hip_runtime.h>
#include <hip/hip_cooperative_groups.h>
#include <hip/hip_bf16.h>
#include <math.h>

namespace cg = cooperative_groups;

#define N_NODES 10000
#define N_EDGES 160000
#define D 512
#define DIN 20
#define B 64
#define KC 10
#define DH 256
#define NROW (B*KC)   // 640
#define BN_EPS 1e-5f

#define ZCOUNT 36352            // csum1,csq1,csum2,csq2 (2048) + s1..q3 (1536) + qemb (32768)
#define Z4 (ZCOUNT/4)           // 9088
#define D4 (N_NODES/4)          // 2500
#define IM_ROWS 8
#define IM_UNITS (N_NODES/IM_ROWS)  // 1250
#define GWAVES 4
#define CGRID 512               // coop grid: 2 blocks/CU guaranteed by launch_bounds(256,2)
#define F1_NS 6
#define F1_ROWS 8
#define F1_KS 256

struct P {
  const float *x, *pg, *neigh, *Winit, *binit;
  const float *g1, *be1, *g2, *be2;
  const float *Wfc, *bfc, *W2, *b2, *W3, *b3, *W4, *b4;
  const float *gbA, *bbA, *gbB, *bbB, *gbC, *bbC;
  const int *esrc, *edst, *n2g;
  unsigned short *hb0, *hb1, *hb2;
  float *zbuf, *csum1, *csq1, *csum2, *csq2;
  float *s1,*q1,*s2,*q2,*s3,*q3, *qemb;
  float *G1,*G2,*G3,*part;
  int *degi,*rowstart,*cursor,*csr,*gstart;
  float *out;
};

__device__ __forceinline__ void f4acc(float4& a, const float4 v){
  a.x += v.x; a.y += v.y; a.z += v.z; a.w += v.w;
}
__device__ __forceinline__ void mk_affine(const float4 s, const float4 q, const float4 g,
                                          const float4 b, float4& sc, float4& sh){
  const float invN = 1.0f/(float)N_NODES;
  float mu, var, rs;
  mu = s.x*invN; var = q.x*invN - mu*mu; rs = rsqrtf(var+BN_EPS); sc.x = rs*g.x; sh.x = b.x - mu*sc.x;
  mu = s.y*invN; var = q.y*invN - mu*mu; rs = rsqrtf(var+BN_EPS); sc.y = rs*g.y; sh.y = b.y - mu*sc.y;
  mu = s.z*invN; var = q.z*invN - mu*mu; rs = rsqrtf(var+BN_EPS); sc.z = rs*g.z; sh.z = b.z - mu*sc.z;
  mu = s.w*invN; var = q.w*invN - mu*mu; rs = rsqrtf(var+BN_EPS); sc.w = rs*g.w; sh.w = b.w - mu*sc.w;
}
__device__ __forceinline__ float4 aff_relu(const float4 v, const float4 sc, const float4 sh){
  float4 o;
  o.x = fmaxf(fmaf(v.x, sc.x, sh.x), 0.0f);
  o.y = fmaxf(fmaf(v.y, sc.y, sh.y), 0.0f);
  o.z = fmaxf(fmaf(v.z, sc.z, sh.z), 0.0f);
  o.w = fmaxf(fmaf(v.w, sc.w, sh.w), 0.0f);
  return o;
}
__device__ __forceinline__ void bf_unpack(const uint4 u, float4& lo, float4& hi){
  lo.x = __uint_as_float(u.x << 16); lo.y = __uint_as_float(u.x & 0xffff0000u);
  lo.z = __uint_as_float(u.y << 16); lo.w = __uint_as_float(u.y & 0xffff0000u);
  hi.x = __uint_as_float(u.z << 16); hi.y = __uint_as_float(u.z & 0xffff0000u);
  hi.z = __uint_as_float(u.w << 16); hi.w = __uint_as_float(u.w & 0xffff0000u);
}
__device__ __forceinline__ unsigned bf_pack2(float a, float b){ // RNE
  unsigned ua = __float_as_uint(a); ua = (ua + 0x7fffu + ((ua>>16)&1u)) >> 16;
  unsigned ub = __float_as_uint(b); ub = (ub + 0x7fffu + ((ub>>16)&1u)) & 0xffff0000u;
  return (ua & 0xffffu) | ub;
}
__device__ __forceinline__ unsigned short bf_pack1(float a){
  unsigned ua = __float_as_uint(a); return (unsigned short)((ua + 0x7fffu + ((ua>>16)&1u)) >> 16);
}

// ================= phases =================
__device__ __forceinline__ void ph_setup(const P& p, int b, int nb, int t){
  for (int i4 = b*256 + t; i4 < Z4 + D4; i4 += nb*256){
    if (i4 < Z4) ((float4*)p.zbuf)[i4] = make_float4(0.f,0.f,0.f,0.f);
    else         ((int4*)p.degi)[i4 - Z4] = make_int4(0,0,0,0);
  }
  if (b == 0 && t <= B){
    int lo = 0, hi = N_NODES;
    while (lo < hi){ int mid = (lo+hi)>>1; if (p.n2g[mid] < t) lo = mid+1; else hi = mid; }
    p.gstart[t] = lo;
  }
}

__device__ __forceinline__ void ph_deg(const P& p, int b, int nb, int t){
  for (int e = b*256 + t; e < N_EDGES; e += nb*256) atomicAdd(&p.degi[p.edst[e]], 1);
}

__device__ __forceinline__ void ph_fill(const P& p, int b, int nb, int t){
  for (int e = b*256 + t; e < N_EDGES; e += nb*256){
    int pos = atomicAdd(&p.cursor[p.edst[e]], 1);
    p.csr[pos] = p.esrc[e];
  }
}

__device__ __forceinline__ void ph_scan(const P& p, int t, int* part){
  const int PER = (N_NODES + 255)/256; // 40
  int base = t*PER;
  int s = 0;
  for (int i = 0; i < PER; ++i){ int idx = base+i; if (idx < N_NODES) s += p.degi[idx]; }
  part[t] = s;
  __syncthreads();
  for (int off = 1; off < 256; off <<= 1){
    int v = (t >= off) ? part[t-off] : 0;
    __syncthreads();
    part[t] += v;
    __syncthreads();
  }
  int run = (t > 0) ? part[t-1] : 0;
  for (int i = 0; i < PER; ++i){
    int idx = base+i;
    if (idx < N_NODES){ p.rowstart[idx] = run; p.cursor[idx] = run; run += p.degi[idx]; }
  }
  if (t == 255) p.rowstart[N_NODES] = run;
}

__device__ __forceinline__ void ph_init(const P& p, int u0, int ustride, int t, float* xs){
  float wlo[DIN], whi[DIN];
  #pragma unroll
  for (int k = 0; k < DIN; ++k){ wlo[k] = p.Winit[k*D + t]; whi[k] = p.Winit[k*D + t + 256]; }
  float b0 = p.binit[t], b1 = p.binit[t+256];
  for (int unit = u0; unit < IM_UNITS; unit += ustride){
    int r0 = unit*IM_ROWS;
    __syncthreads();
    for (int i = t; i < IM_ROWS*DIN; i += 256) xs[i] = p.x[(size_t)r0*DIN + i];
    __syncthreads();
    for (int rr = 0; rr < IM_ROWS; ++rr){
      float a0 = b0, a1 = b1;
      #pragma unroll
      for (int k = 0; k < DIN; ++k){
        float xv = xs[rr*DIN + k];
        a0 += xv*wlo[k]; a1 += xv*whi[k];
      }
      p.hb0[(size_t)(r0+rr)*D + t]       = bf_pack1(a0);
      p.hb0[(size_t)(r0+rr)*D + t + 256] = bf_pack1(a1);
    }
  }
}

template<bool FUSED>
__device__ __forceinline__ void ph_gather(const P& p,
    const unsigned short* __restrict__ hin, unsigned short* __restrict__ hout,
    const float* pcs, const float* pcq, const float* pgm, const float* pbt,
    float* cs, float* cq, int b, int nb, int t, float* red){
  int lane = t & 63;
  int wave = t >> 6;
  int wid  = b*GWAVES + wave;
  int tot  = nb*GWAVES;
  const uint4* hb4 = (const uint4*)hin;   // row stride = 64 uint4
  float4 scA, shA, scB, shB;
  if (FUSED){
    mk_affine(((const float4*)pcs)[2*lane],   ((const float4*)pcq)[2*lane],
              ((const float4*)pgm)[2*lane],   ((const float4*)pbt)[2*lane],   scA, shA);
    mk_affine(((const float4*)pcs)[2*lane+1], ((const float4*)pcq)[2*lane+1],
              ((const float4*)pgm)[2*lane+1], ((const float4*)pbt)[2*lane+1], scB, shB);
  }
  float4 sLo = make_float4(0,0,0,0), sHi = make_float4(0,0,0,0);
  float4 qLo = make_float4(0,0,0,0), qHi = make_float4(0,0,0,0);
  for (int node = wid; node < N_NODES; node += tot){
    int start = p.rowstart[node], end = p.rowstart[node+1];
    float4 aLo = make_float4(0,0,0,0), aHi = make_float4(0,0,0,0);
    float4 bLo = make_float4(0,0,0,0), bHi = make_float4(0,0,0,0);
    for (int base = start; base < end; base += 64){
      int cnt = end - base; if (cnt > 64) cnt = 64;
      int myidx = (lane < cnt) ? p.csr[base+lane] : 0;
      int j = 0;
      for (; j+8 <= cnt; j += 8){
        uint4 u[8];
        #pragma unroll
        for (int k = 0; k < 8; ++k){
          int idx = __shfl(myidx, j+k, 64);
          u[k] = hb4[(size_t)idx*64 + lane];
        }
        #pragma unroll
        for (int k = 0; k < 8; ++k){
          float4 lo, hi; bf_unpack(u[k], lo, hi);
          if (FUSED){ lo = aff_relu(lo, scA, shA); hi = aff_relu(hi, scB, shB); }
          if (k & 1){ f4acc(bLo, lo); f4acc(bHi, hi); }
          else      { f4acc(aLo, lo); f4acc(aHi, hi); }
        }
      }
      for (; j < cnt; ++j){
        int idx = __shfl(myidx, j, 64);
        uint4 u0 = hb4[(size_t)idx*64 + lane];
        float4 lo, hi; bf_unpack(u0, lo, hi);
        if (FUSED){ lo = aff_relu(lo, scA, shA); hi = aff_relu(hi, scB, shB); }
        f4acc(aLo, lo); f4acc(aHi, hi);
      }
    }
    float inv = 1.0f/fmaxf((float)(end-start), 1.0f);
    uint4 us = hb4[(size_t)node*64 + lane];
    float4 hLo, hHi; bf_unpack(us, hLo, hHi);
    if (FUSED){ hLo = aff_relu(hLo, scA, shA); hHi = aff_relu(hHi, scB, shB); }
    float4 oLo, oHi;
    oLo.x = hLo.x + (aLo.x+bLo.x)*inv;  oLo.y = hLo.y + (aLo.y+bLo.y)*inv;
    oLo.z = hLo.z + (aLo.z+bLo.z)*inv;  oLo.w = hLo.w + (aLo.w+bLo.w)*inv;
    oHi.x = hHi.x + (aHi.x+bHi.x)*inv;  oHi.y = hHi.y + (aHi.y+bHi.y)*inv;
    oHi.z = hHi.z + (aHi.z+bHi.z)*inv;  oHi.w = hHi.w + (aHi.w+bHi.w)*inv;
    uint4 ou;
    ou.x = bf_pack2(oLo.x, oLo.y); ou.y = bf_pack2(oLo.z, oLo.w);
    ou.z = bf_pack2(oHi.x, oHi.y); ou.w = bf_pack2(oHi.z, oHi.w);
    ((uint4*)hout)[(size_t)node*64 + lane] = ou;
    f4acc(sLo, oLo); f4acc(sHi, oHi);
    qLo.x += oLo.x*oLo.x; qLo.y += oLo.y*oLo.y; qLo.z += oLo.z*oLo.z; qLo.w += oLo.w*oLo.w;
    qHi.x += oHi.x*oHi.x; qHi.y += oHi.y*oHi.y; qHi.z += oHi.z*oHi.z; qHi.w += oHi.w*oHi.w;
  }
  float* my = red + wave*1024;
  int c = 8*lane;
  *((float4*)&my[c])      = sLo;  *((float4*)&my[c+4])     = sHi;
  *((float4*)&my[512+c])  = qLo;  *((float4*)&my[512+c+4]) = qHi;
  __syncthreads();
  for (int e = t; e < 1024; e += 256){
    float v = red[e] + red[1024+e] + red[2048+e] + red[3072+e];
    if (e < 512) atomicAdd(&cs[e], v);
    else         atomicAdd(&cq[e-512], v);
  }
}

__device__ __forceinline__ void ph_readout(const P& p, int b, int t, float* red){
  int g = b >> 3, chunk = b & 7;
  int lane = t & 63, wave = t >> 6;
  const uint4* hb4 = (const uint4*)p.hb2;
  float4 scA, shA, scB, shB;
  mk_affine(((const float4*)p.csum2)[2*lane],   ((const float4*)p.csq2)[2*lane],
            ((const float4*)p.g2)[2*lane],      ((const float4*)p.be2)[2*lane],   scA, shA);
  mk_affine(((const float4*)p.csum2)[2*lane+1], ((const float4*)p.csq2)[2*lane+1],
            ((const float4*)p.g2)[2*lane+1],    ((const float4*)p.be2)[2*lane+1], scB, shB);
  int s = p.gstart[g], e = p.gstart[g+1];
  int rows = e - s;
  int per = (rows + 7)/8;
  int r0 = s + chunk*per;
  int r1 = r0 + per; if (r1 > e) r1 = e;
  float4 aLo = make_float4(0,0,0,0), aHi = make_float4(0,0,0,0);
  for (int r = r0 + wave; r < r1; r += 4){
    uint4 u = hb4[(size_t)r*64 + lane];
    float4 lo, hi; bf_unpack(u, lo, hi);
    lo = aff_relu(lo, scA, shA); hi = aff_relu(hi, scB, shB);
    f4acc(aLo, lo); f4acc(aHi, hi);
  }
  int c = 8*lane;
  *((float4*)&red[wave*512 + c])     = aLo;
  *((float4*)&red[wave*512 + c + 4]) = aHi;
  __syncthreads();
  for (int e2 = t; e2 < 512; e2 += 256){
    float v = red[e2] + red[512+e2] + red[1024+e2] + red[1536+e2];
    atomicAdd(&p.qemb[(size_t)g*D + e2], v);
  }
}

__device__ __forceinline__ void ph_fc1(const P& p, int u, int t, float* brow){
  int rb = u % 80, ks = u / 80;
  int r0 = rb*F1_ROWS, k0 = ks*F1_KS;
  for (int rr = 0; rr < F1_ROWS; ++rr){
    int r = r0+rr;
    int g = r/KC, k = r - g*KC;
    int j = k0 + t;
    float v;
    if (j < D){
      float invc = 1.0f/fmaxf((float)(p.gstart[g+1]-p.gstart[g]), 1.0f);
      v = p.qemb[(size_t)g*D + j]*invc;
    } else if (j < 2*D){
      v = p.pg[(size_t)g*D + (j-D)];
    } else {
      v = p.neigh[((size_t)g*KC + k)*D + (j-2*D)];
    }
    brow[rr*F1_KS + t] = v;
  }
  __syncthreads();
  float acc[F1_ROWS] = {0.f,0.f,0.f,0.f,0.f,0.f,0.f,0.f};
  #pragma unroll 4
  for (int kk = 0; kk < F1_KS; ++kk){
    float w = p.Wfc[(size_t)(k0+kk)*DH + t];
    #pragma unroll
    for (int rr = 0; rr < F1_ROWS; ++rr) acc[rr] += brow[rr*F1_KS + kk]*w;
  }
  for (int rr = 0; rr < F1_ROWS; ++rr)
    p.part[((size_t)ks*NROW + r0+rr)*DH + t] = acc[rr];
}

__device__ __forceinline__ void ph_reduce(const float* part, const float* bias,
                                          float* outG, float* s, float* q, int u, int t){
  int r0 = u*8;
  float bval = bias[t];
  float ls = 0.f, lq = 0.f;
  for (int rr = 0; rr < 8; ++rr){
    int r = r0+rr;
    float acc = bval;
    for (int sl = 0; sl < F1_NS; ++sl) acc += part[((size_t)sl*NROW + r)*DH + t];
    outG[(size_t)r*DH + t] = acc;
    ls += acc; lq += acc*acc;
  }
  atomicAdd(&s[t], ls); atomicAdd(&q[t], lq);
}

__device__ __forceinline__ void ph_fcmid(const float* in, const float* ps, const float* pq,
    const float* gamma, const float* beta, const float* W, const float* bias,
    float* outG, float* s, float* q, int u, int t, float* row){
  int r0 = u*4;
  const float invM = 1.0f/(float)NROW;
  #pragma unroll
  for (int i = 0; i < 4; ++i){
    int idx = t + i*256;
    int rr = idx >> 8, kk = idx & 255;
    float mu = ps[kk]*invM;
    float var = pq[kk]*invM - mu*mu;
    float rs = rsqrtf(var + BN_EPS);
    float v = in[(size_t)(r0+rr)*DH + kk];
    row[rr*DH + kk] = fmaxf((v-mu)*rs*gamma[kk] + beta[kk], 0.0f);
  }
  __syncthreads();
  float bv = bias[t];
  float a0 = bv, a1 = bv, a2 = bv, a3 = bv;
  #pragma unroll 4
  for (int kk = 0; kk < DH; ++kk){
    float w = W[(size_t)kk*DH + t];
    a0 += row[0*DH+kk]*w; a1 += row[1*DH+kk]*w;
    a2 += row[2*DH+kk]*w; a3 += row[3*DH+kk]*w;
  }
  outG[(size_t)(r0+0)*DH + t] = a0;
  outG[(size_t)(r0+1)*DH + t] = a1;
  outG[(size_t)(r0+2)*DH + t] = a2;
  outG[(size_t)(r0+3)*DH + t] = a3;
  float ls = a0+a1+a2+a3;
  float lq = a0*a0 + a1*a1 + a2*a2 + a3*a3;
  atomicAdd(&s[t], ls); atomicAdd(&q[t], lq);
}

__device__ __forceinline__ void ph_final(const P& p, int u, int t){
  int wave = t>>6, lane = t&63;
  int r = u*4 + wave;
  const float invM = 1.0f/(float)NROW;
  float sum = 0.f;
  #pragma unroll
  for (int j = 0; j < 4; ++j){
    int c = lane + 64*j;
    float mu = p.s3[c]*invM;
    float var = p.q3[c]*invM - mu*mu;
    float rs = rsqrtf(var+BN_EPS);
    float v = p.G3[(size_t)r*DH + c];
    v = fmaxf((v-mu)*rs*p.gbC[c] + p.bbC[c], 0.0f);
    sum += v*p.W4[c];
  }
  #pragma unroll
  for (int off = 32; off > 0; off >>= 1) sum += __shfl_down(sum, off, 64);
  if (lane == 0){
    float z = sum + p.b4[0];
    p.out[r] = 1.0f/(1.0f + expf(-z));
  }
}

// ================= cooperative kernels =================
__global__ __launch_bounds__(256, 2)
void coopA(P p){
  cg::grid_group grid = cg::this_grid();
  __shared__ float lds[4096];   // 16 KB
  int b = blockIdx.x, nb = gridDim.x, t = threadIdx.x;
  ph_setup(p, b, nb, t);
  grid.sync();
  ph_deg(p, b, nb, t);
  grid.sync();
  if (b == 0) ph_scan(p, t, (int*)lds);
  else        ph_init(p, b-1, nb-1, t, lds);
  grid.sync();
  ph_fill(p, b, nb, t);
  grid.sync();
  ph_gather<false>(p, p.hb0, p.hb1, nullptr,nullptr,nullptr,nullptr,
                   p.csum1, p.csq1, b, nb, t, lds);
}

__global__ __launch_bounds__(256, 2)
void coopB(P p){
  cg::grid_group grid = cg::this_grid();
  __shared__ float lds[4096];   // 16 KB
  int b = blockIdx.x, nb = gridDim.x, t = threadIdx.x;
  ph_gather<true>(p, p.hb1, p.hb2, p.csum1, p.csq1, p.g1, p.be1,
                  p.csum2, p.csq2, b, nb, t, lds);
  grid.sync();
  ph_readout(p, b, t, lds);      // needs exactly 512 blocks
  grid.sync();
  if (b < 480) ph_fc1(p, b, t, lds);
  grid.sync();
  if (b < 80) ph_reduce(p.part, p.bfc, p.G1, p.s1, p.q1, b, t);
  grid.sync();
  if (b < 160) ph_fcmid(p.G1, p.s1, p.q1, p.gbA, p.bbA, p.W2, p.b2, p.G2, p.s2, p.q2, b, t, lds);
  grid.sync();
  if (b < 160) ph_fcmid(p.G2, p.s2, p.q2, p.gbB, p.bbB, p.W3, p.b3, p.G3, p.s3, p.q3, b, t, lds);
  grid.sync();
  if (b < 160) ph_final(p, b, t);
}

// ================= fallback discrete kernels =================
__global__ __launch_bounds__(256,2) void k_setup(P p){ ph_setup(p, blockIdx.x, gridDim.x, threadIdx.x); }
__global__ __launch_bounds__(256,2) void k_deg(P p){ ph_deg(p, blockIdx.x, gridDim.x, threadIdx.x); }
__global__ __launch_bounds__(256,2) void k_scan(P p){ __shared__ int il[256]; ph_scan(p, threadIdx.x, il); }
__global__ __launch_bounds__(256,2) void k_init(P p){ __shared__ float xs[IM_ROWS*DIN]; ph_init(p, blockIdx.x, gridDim.x, threadIdx.x, xs); }
__global__ __launch_bounds__(256,2) void k_fill(P p){ ph_fill(p, blockIdx.x, gridDim.x, threadIdx.x); }
__global__ __launch_bounds__(256,2) void k_g1(P p){ __shared__ float red[4096];
  ph_gather<false>(p, p.hb0, p.hb1, nullptr,nullptr,nullptr,nullptr, p.csum1, p.csq1,
                   blockIdx.x, gridDim.x, threadIdx.x, red); }
__global__ __launch_bounds__(256,2) void k_g2(P p){ __shared__ float red[4096];
  ph_gather<true>(p, p.hb1, p.hb2, p.csum1, p.csq1, p.g1, p.be1, p.csum2, p.csq2,
                  blockIdx.x, gridDim.x, threadIdx.x, red); }
__global__ __launch_bounds__(256,2) void k_readout(P p){ __shared__ float red[2048]; ph_readout(p, blockIdx.x, threadIdx.x, red); }
__global__ __launch_bounds__(256,2) void k_fc1(P p){ __shared__ float brow[2048]; ph_fc1(p, blockIdx.x, threadIdx.x, brow); }
__global__ __launch_bounds__(256,2) void k_reduce(P p){ ph_reduce(p.part, p.bfc, p.G1, p.s1, p.q1, blockIdx.x, threadIdx.x); }
__global__ __launch_bounds__(256,2) void k_fc2(P p){ __shared__ float row[1024];
  ph_fcmid(p.G1, p.s1, p.q1, p.gbA, p.bbA, p.W2, p.b2, p.G2, p.s2, p.q2, blockIdx.x, threadIdx.x, row); }
__global__ __launch_bounds__(256,2) void k_fc3(P p){ __shared__ float row[1024];
  ph_fcmid(p.G2, p.s2, p.q2, p.gbB, p.bbB, p.W3, p.b3, p.G3, p.s3, p.q3, blockIdx.x, threadIdx.x, row); }
__global__ __launch_bounds__(256,2) void k_final(P p){ ph_final(p, blockIdx.x, threadIdx.x); }

extern "C" void kernel_launch(void* const* d_in, const int* in_sizes, int n_in,
                              void* d_out, int out_size, void* d_ws, size_t ws_size,
                              hipStream_t stream) {
  P p;
  p.x     = (const float*)d_in[0];
  p.pg    = (const float*)d_in[1];
  p.neigh = (const float*)d_in[2];
  p.Winit = (const float*)d_in[3];
  p.binit = (const float*)d_in[4];
  p.g1    = (const float*)d_in[5];
  p.be1   = (const float*)d_in[6];
  p.g2    = (const float*)d_in[7];
  p.be2   = (const float*)d_in[8];
  p.Wfc   = (const float*)d_in[9];
  p.bfc   = (const float*)d_in[10];
  p.W2    = (const float*)d_in[11];
  p.b2    = (const float*)d_in[12];
  p.W3    = (const float*)d_in[13];
  p.b3    = (const float*)d_in[14];
  p.W4    = (const float*)d_in[15];
  p.b4    = (const float*)d_in[16];
  p.gbA   = (const float*)d_in[17];
  p.bbA   = (const float*)d_in[18];
  p.gbB   = (const float*)d_in[19];
  p.bbB   = (const float*)d_in[20];
  p.gbC   = (const float*)d_in[21];
  p.bbC   = (const float*)d_in[22];
  p.esrc  = (const int*)d_in[23];
  p.edst  = (const int*)d_in[24];
  p.n2g   = (const int*)d_in[25];
  p.out   = (float*)d_out;

  float* ws = (float*)d_ws;
  size_t off = 0;
  p.hb0 = (unsigned short*)(ws + off); off += (size_t)N_NODES*D/2;
  p.hb1 = (unsigned short*)(ws + off); off += (size_t)N_NODES*D/2;
  p.hb2 = (unsigned short*)(ws + off); off += (size_t)N_NODES*D/2;
  p.zbuf  = ws + off;                 // zero region start
  p.csum1 = ws + off; off += 512;
  p.csq1  = ws + off; off += 512;
  p.csum2 = ws + off; off += 512;
  p.csq2  = ws + off; off += 512;
  p.s1    = ws + off; off += 256;
  p.q1    = ws + off; off += 256;
  p.s2    = ws + off; off += 256;
  p.q2    = ws + off; off += 256;
  p.s3    = ws + off; off += 256;
  p.q3    = ws + off; off += 256;
  p.qemb  = ws + off; off += (size_t)B*D;   // end zero region (ZCOUNT floats total)
  p.G1   = ws + off; off += (size_t)NROW*DH;
  p.G2   = ws + off; off += (size_t)NROW*DH;
  p.G3   = ws + off; off += (size_t)NROW*DH;
  p.part = ws + off; off += (size_t)F1_NS*NROW*DH;
  p.degi     = (int*)(ws + off); off += N_NODES;
  p.rowstart = (int*)(ws + off); off += N_NODES + 1;
  p.cursor   = (int*)(ws + off); off += N_NODES;
  p.csr      = (int*)(ws + off); off += N_EDGES;
  p.gstart   = (int*)(ws + off); off += B + 1;

  void* args[] = { &p };
  hipError_t e1 = hipLaunchCooperativeKernel((void*)coopA, dim3(CGRID), dim3(256), args, 0, stream);
  if (e1 != hipSuccess){
    k_setup<<<64, 256, 0, stream>>>(p);
    k_deg<<<625, 256, 0, stream>>>(p);
    k_scan<<<1, 256, 0, stream>>>(p);
    k_init<<<625, 256, 0, stream>>>(p);
    k_fill<<<625, 256, 0, stream>>>(p);
    k_g1<<<625, 256, 0, stream>>>(p);
  }
  hipError_t e2 = hipLaunchCooperativeKernel((void*)coopB, dim3(CGRID), dim3(256), args, 0, stream);
  if (e2 != hipSuccess){
    k_g2<<<625, 256, 0, stream>>>(p);
    k_readout<<<512, 256, 0, stream>>>(p);
    k_fc1<<<480, 256, 0, stream>>>(p);
    k_reduce<<<80, 256, 0, stream>>>(p);
    k_fc2<<<160, 256, 0, stream>>>(p);
    k_fc3<<<160, 256, 0, stream>>>(p);
    k_final<<<160, 256, 0, stream>>>(p);
  }
}

// Round 9
// 255.307 us; speedup vs baseline: 2.9887x; 2.9887x over previous
//
#include <hip/hip_runtime.h>
#include <hip/hip_bf16.h>
#include <math.h>

#define N_NODES 10000
#define N_EDGES 160000
#define D 512
#define DIN 20
#define B 64
#define KC 10
#define DH 256
#define NROW (B*KC)   // 640
#define BN_EPS 1e-5f

#define ZCOUNT 36352            // csum1,csq1,csum2,csq2 (2048) + s1..q3 (1536) + qemb (32768)
#define Z4 (ZCOUNT/4)           // 9088
#define D4 (N_NODES/4)          // 2500
#define IM_ROWS 8
#define IM_UNITS (N_NODES/IM_ROWS)  // 1250
#define GWAVES 4
#define GBLOCKS 1250            // gather grid: ~5 blocks/CU
#define F1_NS 6
#define F1_ROWS 8
#define F1_KS 256

struct P {
  const float *x, *pg, *neigh, *Winit, *binit;
  const float *g1, *be1, *g2, *be2;
  const float *Wfc, *bfc, *W2, *b2, *W3, *b3, *W4, *b4;
  const float *gbA, *bbA, *gbB, *bbB, *gbC, *bbC;
  const int *esrc, *edst, *n2g;
  unsigned short *hb0, *hb1, *hb2;
  float *zbuf, *csum1, *csq1, *csum2, *csq2;
  float *s1,*q1,*s2,*q2,*s3,*q3, *qemb;
  float *G1,*G2,*G3,*part;
  int *degi,*rowstart,*cursor,*csr,*gstart;
  float *out;
};

__device__ __forceinline__ void f4acc(float4& a, const float4 v){
  a.x += v.x; a.y += v.y; a.z += v.z; a.w += v.w;
}
__device__ __forceinline__ void mk_affine(const float4 s, const float4 q, const float4 g,
                                          const float4 b, float4& sc, float4& sh){
  const float invN = 1.0f/(float)N_NODES;
  float mu, var, rs;
  mu = s.x*invN; var = q.x*invN - mu*mu; rs = rsqrtf(var+BN_EPS); sc.x = rs*g.x; sh.x = b.x - mu*sc.x;
  mu = s.y*invN; var = q.y*invN - mu*mu; rs = rsqrtf(var+BN_EPS); sc.y = rs*g.y; sh.y = b.y - mu*sc.y;
  mu = s.z*invN; var = q.z*invN - mu*mu; rs = rsqrtf(var+BN_EPS); sc.z = rs*g.z; sh.z = b.z - mu*sc.z;
  mu = s.w*invN; var = q.w*invN - mu*mu; rs = rsqrtf(var+BN_EPS); sc.w = rs*g.w; sh.w = b.w - mu*sc.w;
}
__device__ __forceinline__ float4 aff_relu(const float4 v, const float4 sc, const float4 sh){
  float4 o;
  o.x = fmaxf(fmaf(v.x, sc.x, sh.x), 0.0f);
  o.y = fmaxf(fmaf(v.y, sc.y, sh.y), 0.0f);
  o.z = fmaxf(fmaf(v.z, sc.z, sh.z), 0.0f);
  o.w = fmaxf(fmaf(v.w, sc.w, sh.w), 0.0f);
  return o;
}
__device__ __forceinline__ void bf_unpack(const uint4 u, float4& lo, float4& hi){
  lo.x = __uint_as_float(u.x << 16); lo.y = __uint_as_float(u.x & 0xffff0000u);
  lo.z = __uint_as_float(u.y << 16); lo.w = __uint_as_float(u.y & 0xffff0000u);
  hi.x = __uint_as_float(u.z << 16); hi.y = __uint_as_float(u.z & 0xffff0000u);
  hi.z = __uint_as_float(u.w << 16); hi.w = __uint_as_float(u.w & 0xffff0000u);
}
__device__ __forceinline__ unsigned bf_pack2(float a, float b){ // RNE
  unsigned ua = __float_as_uint(a); ua = (ua + 0x7fffu + ((ua>>16)&1u)) >> 16;
  unsigned ub = __float_as_uint(b); ub = (ub + 0x7fffu + ((ub>>16)&1u)) & 0xffff0000u;
  return (ua & 0xffffu) | ub;
}
__device__ __forceinline__ unsigned short bf_pack1(float a){
  unsigned ua = __float_as_uint(a); return (unsigned short)((ua + 0x7fffu + ((ua>>16)&1u)) >> 16);
}

// ================= kernels =================
__global__ __launch_bounds__(256) void k_setup(P p){
  int b = blockIdx.x, nb = gridDim.x, t = threadIdx.x;
  for (int i4 = b*256 + t; i4 < Z4 + D4; i4 += nb*256){
    if (i4 < Z4) ((float4*)p.zbuf)[i4] = make_float4(0.f,0.f,0.f,0.f);
    else         ((int4*)p.degi)[i4 - Z4] = make_int4(0,0,0,0);
  }
  if (b == 0 && t <= B){
    int lo = 0, hi = N_NODES;
    while (lo < hi){ int mid = (lo+hi)>>1; if (p.n2g[mid] < t) lo = mid+1; else hi = mid; }
    p.gstart[t] = lo;
  }
}

__global__ __launch_bounds__(256) void k_deg(P p){
  int e = blockIdx.x*256 + threadIdx.x;
  if (e < N_EDGES) atomicAdd(&p.degi[p.edst[e]], 1);
}

__global__ __launch_bounds__(256) void k_scan(P p){
  __shared__ int part[256];
  int t = threadIdx.x;
  const int PER = (N_NODES + 255)/256; // 40
  int base = t*PER;
  int s = 0;
  for (int i = 0; i < PER; ++i){ int idx = base+i; if (idx < N_NODES) s += p.degi[idx]; }
  part[t] = s;
  __syncthreads();
  for (int off = 1; off < 256; off <<= 1){
    int v = (t >= off) ? part[t-off] : 0;
    __syncthreads();
    part[t] += v;
    __syncthreads();
  }
  int run = (t > 0) ? part[t-1] : 0;
  for (int i = 0; i < PER; ++i){
    int idx = base+i;
    if (idx < N_NODES){ p.rowstart[idx] = run; p.cursor[idx] = run; run += p.degi[idx]; }
  }
  if (t == 255) p.rowstart[N_NODES] = run;
}

__global__ __launch_bounds__(256) void k_fill(P p){
  int e = blockIdx.x*256 + threadIdx.x;
  if (e < N_EDGES){
    int pos = atomicAdd(&p.cursor[p.edst[e]], 1);
    p.csr[pos] = p.esrc[e];
  }
}

// W_init held in registers (40 VGPRs), one 8-row unit per block
__global__ __launch_bounds__(256) void k_init(P p){
  __shared__ float xs[IM_ROWS*DIN];
  int t = threadIdx.x;
  float wlo[DIN], whi[DIN];
  #pragma unroll
  for (int k = 0; k < DIN; ++k){ wlo[k] = p.Winit[k*D + t]; whi[k] = p.Winit[k*D + t + 256]; }
  float b0 = p.binit[t], b1 = p.binit[t+256];
  int r0 = blockIdx.x*IM_ROWS;
  for (int i = t; i < IM_ROWS*DIN; i += 256) xs[i] = p.x[(size_t)r0*DIN + i];
  __syncthreads();
  for (int rr = 0; rr < IM_ROWS; ++rr){
    float a0 = b0, a1 = b1;
    #pragma unroll
    for (int k = 0; k < DIN; ++k){
      float xv = xs[rr*DIN + k];
      a0 += xv*wlo[k]; a1 += xv*whi[k];
    }
    p.hb0[(size_t)(r0+rr)*D + t]       = bf_pack1(a0);
    p.hb0[(size_t)(r0+rr)*D + t + 256] = bf_pack1(a1);
  }
}

template<bool FUSED>
__device__ __forceinline__ void gather_body(const P& p,
    const unsigned short* __restrict__ hin, unsigned short* __restrict__ hout,
    const float* pcs, const float* pcq, const float* pgm, const float* pbt,
    float* cs, float* cq, float* red){
  int t = threadIdx.x;
  int lane = t & 63;
  int wave = t >> 6;
  int wid  = blockIdx.x*GWAVES + wave;
  int tot  = gridDim.x*GWAVES;
  const uint4* hb4 = (const uint4*)hin;   // row stride = 64 uint4
  float4 scA, shA, scB, shB;
  if (FUSED){
    mk_affine(((const float4*)pcs)[2*lane],   ((const float4*)pcq)[2*lane],
              ((const float4*)pgm)[2*lane],   ((const float4*)pbt)[2*lane],   scA, shA);
    mk_affine(((const float4*)pcs)[2*lane+1], ((const float4*)pcq)[2*lane+1],
              ((const float4*)pgm)[2*lane+1], ((const float4*)pbt)[2*lane+1], scB, shB);
  }
  float4 sLo = make_float4(0,0,0,0), sHi = make_float4(0,0,0,0);
  float4 qLo = make_float4(0,0,0,0), qHi = make_float4(0,0,0,0);
  for (int node = wid; node < N_NODES; node += tot){
    int start = p.rowstart[node], end = p.rowstart[node+1];
    float4 aLo = make_float4(0,0,0,0), aHi = make_float4(0,0,0,0);
    float4 bLo = make_float4(0,0,0,0), bHi = make_float4(0,0,0,0);
    for (int base = start; base < end; base += 64){
      int cnt = end - base; if (cnt > 64) cnt = 64;
      int myidx = (lane < cnt) ? p.csr[base+lane] : 0;
      int j = 0;
      for (; j+8 <= cnt; j += 8){
        uint4 u[8];
        #pragma unroll
        for (int k = 0; k < 8; ++k){
          int idx = __shfl(myidx, j+k, 64);
          u[k] = hb4[(size_t)idx*64 + lane];
        }
        #pragma unroll
        for (int k = 0; k < 8; ++k){
          float4 lo, hi; bf_unpack(u[k], lo, hi);
          if (FUSED){ lo = aff_relu(lo, scA, shA); hi = aff_relu(hi, scB, shB); }
          if (k & 1){ f4acc(bLo, lo); f4acc(bHi, hi); }
          else      { f4acc(aLo, lo); f4acc(aHi, hi); }
        }
      }
      for (; j < cnt; ++j){
        int idx = __shfl(myidx, j, 64);
        uint4 u0 = hb4[(size_t)idx*64 + lane];
        float4 lo, hi; bf_unpack(u0, lo, hi);
        if (FUSED){ lo = aff_relu(lo, scA, shA); hi = aff_relu(hi, scB, shB); }
        f4acc(aLo, lo); f4acc(aHi, hi);
      }
    }
    float inv = 1.0f/fmaxf((float)(end-start), 1.0f);
    uint4 us = hb4[(size_t)node*64 + lane];
    float4 hLo, hHi; bf_unpack(us, hLo, hHi);
    if (FUSED){ hLo = aff_relu(hLo, scA, shA); hHi = aff_relu(hHi, scB, shB); }
    float4 oLo, oHi;
    oLo.x = hLo.x + (aLo.x+bLo.x)*inv;  oLo.y = hLo.y + (aLo.y+bLo.y)*inv;
    oLo.z = hLo.z + (aLo.z+bLo.z)*inv;  oLo.w = hLo.w + (aLo.w+bLo.w)*inv;
    oHi.x = hHi.x + (aHi.x+bHi.x)*inv;  oHi.y = hHi.y + (aHi.y+bHi.y)*inv;
    oHi.z = hHi.z + (aHi.z+bHi.z)*inv;  oHi.w = hHi.w + (aHi.w+bHi.w)*inv;
    uint4 ou;
    ou.x = bf_pack2(oLo.x, oLo.y); ou.y = bf_pack2(oLo.z, oLo.w);
    ou.z = bf_pack2(oHi.x, oHi.y); ou.w = bf_pack2(oHi.z, oHi.w);
    ((uint4*)hout)[(size_t)node*64 + lane] = ou;
    f4acc(sLo, oLo); f4acc(sHi, oHi);
    qLo.x += oLo.x*oLo.x; qLo.y += oLo.y*oLo.y; qLo.z += oLo.z*oLo.z; qLo.w += oLo.w*oLo.w;
    qHi.x += oHi.x*oHi.x; qHi.y += oHi.y*oHi.y; qHi.z += oHi.z*oHi.z; qHi.w += oHi.w*oHi.w;
  }
  float* my = red + wave*1024;
  int c = 8*lane;
  *((float4*)&my[c])      = sLo;  *((float4*)&my[c+4])     = sHi;
  *((float4*)&my[512+c])  = qLo;  *((float4*)&my[512+c+4]) = qHi;
  __syncthreads();
  for (int e = t; e < 1024; e += 256){
    float v = red[e] + red[1024+e] + red[2048+e] + red[3072+e];
    if (e < 512) atomicAdd(&cs[e], v);
    else         atomicAdd(&cq[e-512], v);
  }
}

__global__ __launch_bounds__(256) void k_g1(P p){
  __shared__ float red[4096];
  gather_body<false>(p, p.hb0, p.hb1, nullptr,nullptr,nullptr,nullptr, p.csum1, p.csq1, red);
}
__global__ __launch_bounds__(256) void k_g2(P p){
  __shared__ float red[4096];
  gather_body<true>(p, p.hb1, p.hb2, p.csum1, p.csq1, p.g1, p.be1, p.csum2, p.csq2, red);
}

__global__ __launch_bounds__(256) void k_readout(P p){
  __shared__ float red[2048];
  int g = blockIdx.x >> 3, chunk = blockIdx.x & 7;
  int t = threadIdx.x;
  int lane = t & 63, wave = t >> 6;
  const uint4* hb4 = (const uint4*)p.hb2;
  float4 scA, shA, scB, shB;
  mk_affine(((const float4*)p.csum2)[2*lane],   ((const float4*)p.csq2)[2*lane],
            ((const float4*)p.g2)[2*lane],      ((const float4*)p.be2)[2*lane],   scA, shA);
  mk_affine(((const float4*)p.csum2)[2*lane+1], ((const float4*)p.csq2)[2*lane+1],
            ((const float4*)p.g2)[2*lane+1],    ((const float4*)p.be2)[2*lane+1], scB, shB);
  int s = p.gstart[g], e = p.gstart[g+1];
  int rows = e - s;
  int per = (rows + 7)/8;
  int r0 = s + chunk*per;
  int r1 = r0 + per; if (r1 > e) r1 = e;
  float4 aLo = make_float4(0,0,0,0), aHi = make_float4(0,0,0,0);
  for (int r = r0 + wave; r < r1; r += 4){
    uint4 u = hb4[(size_t)r*64 + lane];
    float4 lo, hi; bf_unpack(u, lo, hi);
    lo = aff_relu(lo, scA, shA); hi = aff_relu(hi, scB, shB);
    f4acc(aLo, lo); f4acc(aHi, hi);
  }
  int c = 8*lane;
  *((float4*)&red[wave*512 + c])     = aLo;
  *((float4*)&red[wave*512 + c + 4]) = aHi;
  __syncthreads();
  for (int e2 = t; e2 < 512; e2 += 256){
    float v = red[e2] + red[512+e2] + red[1024+e2] + red[1536+e2];
    atomicAdd(&p.qemb[(size_t)g*D + e2], v);
  }
}

__global__ __launch_bounds__(256) void k_fc1(P p){
  __shared__ float brow[F1_ROWS*F1_KS];
  int t = threadIdx.x;
  int rb = blockIdx.x % 80, ks = blockIdx.x / 80;
  int r0 = rb*F1_ROWS, k0 = ks*F1_KS;
  for (int rr = 0; rr < F1_ROWS; ++rr){
    int r = r0+rr;
    int g = r/KC, k = r - g*KC;
    int j = k0 + t;
    float v;
    if (j < D){
      float invc = 1.0f/fmaxf((float)(p.gstart[g+1]-p.gstart[g]), 1.0f);
      v = p.qemb[(size_t)g*D + j]*invc;
    } else if (j < 2*D){
      v = p.pg[(size_t)g*D + (j-D)];
    } else {
      v = p.neigh[((size_t)g*KC + k)*D + (j-2*D)];
    }
    brow[rr*F1_KS + t] = v;
  }
  __syncthreads();
  float acc[F1_ROWS] = {0.f,0.f,0.f,0.f,0.f,0.f,0.f,0.f};
  #pragma unroll 4
  for (int kk = 0; kk < F1_KS; ++kk){
    float w = p.Wfc[(size_t)(k0+kk)*DH + t];
    #pragma unroll
    for (int rr = 0; rr < F1_ROWS; ++rr) acc[rr] += brow[rr*F1_KS + kk]*w;
  }
  for (int rr = 0; rr < F1_ROWS; ++rr)
    p.part[((size_t)ks*NROW + r0+rr)*DH + t] = acc[rr];
}

__global__ __launch_bounds__(256) void k_reduce(P p){
  int t = threadIdx.x;
  int r0 = blockIdx.x*8;
  float bval = p.bfc[t];
  float ls = 0.f, lq = 0.f;
  for (int rr = 0; rr < 8; ++rr){
    int r = r0+rr;
    float acc = bval;
    for (int sl = 0; sl < F1_NS; ++sl) acc += p.part[((size_t)sl*NROW + r)*DH + t];
    p.G1[(size_t)r*DH + t] = acc;
    ls += acc; lq += acc*acc;
  }
  atomicAdd(&p.s1[t], ls); atomicAdd(&p.q1[t], lq);
}

// 1 row per block
__device__ __forceinline__ void fcmid_body(const float* in, const float* ps, const float* pq,
    const float* gamma, const float* beta, const float* W, const float* bias,
    float* outG, float* s, float* q, float* row){
  int t = threadIdx.x;
  int r = blockIdx.x;
  const float invM = 1.0f/(float)NROW;
  {
    float mu = ps[t]*invM;
    float var = pq[t]*invM - mu*mu;
    float rs = rsqrtf(var + BN_EPS);
    float v = in[(size_t)r*DH + t];
    row[t] = fmaxf((v-mu)*rs*gamma[t] + beta[t], 0.0f);
  }
  __syncthreads();
  float acc = bias[t];
  #pragma unroll 8
  for (int kk = 0; kk < DH; ++kk)
    acc += row[kk]*W[(size_t)kk*DH + t];
  outG[(size_t)r*DH + t] = acc;
  atomicAdd(&s[t], acc); atomicAdd(&q[t], acc*acc);
}
__global__ __launch_bounds__(256) void k_fc2(P p){ __shared__ float row[DH];
  fcmid_body(p.G1, p.s1, p.q1, p.gbA, p.bbA, p.W2, p.b2, p.G2, p.s2, p.q2, row); }
__global__ __launch_bounds__(256) void k_fc3(P p){ __shared__ float row[DH];
  fcmid_body(p.G2, p.s2, p.q2, p.gbB, p.bbB, p.W3, p.b3, p.G3, p.s3, p.q3, row); }

__global__ __launch_bounds__(256) void k_final(P p){
  int t = threadIdx.x;
  int wave = t>>6, lane = t&63;
  int r = blockIdx.x*4 + wave;
  const float invM = 1.0f/(float)NROW;
  float sum = 0.f;
  #pragma unroll
  for (int j = 0; j < 4; ++j){
    int c = lane + 64*j;
    float mu = p.s3[c]*invM;
    float var = p.q3[c]*invM - mu*mu;
    float rs = rsqrtf(var+BN_EPS);
    float v = p.G3[(size_t)r*DH + c];
    v = fmaxf((v-mu)*rs*p.gbC[c] + p.bbC[c], 0.0f);
    sum += v*p.W4[c];
  }
  #pragma unroll
  for (int off = 32; off > 0; off >>= 1) sum += __shfl_down(sum, off, 64);
  if (lane == 0){
    float z = sum + p.b4[0];
    p.out[r] = 1.0f/(1.0f + expf(-z));
  }
}

extern "C" void kernel_launch(void* const* d_in, const int* in_sizes, int n_in,
                              void* d_out, int out_size, void* d_ws, size_t ws_size,
                              hipStream_t stream) {
  P p;
  p.x     = (const float*)d_in[0];
  p.pg    = (const float*)d_in[1];
  p.neigh = (const float*)d_in[2];
  p.Winit = (const float*)d_in[3];
  p.binit = (const float*)d_in[4];
  p.g1    = (const float*)d_in[5];
  p.be1   = (const float*)d_in[6];
  p.g2    = (const float*)d_in[7];
  p.be2   = (const float*)d_in[8];
  p.Wfc   = (const float*)d_in[9];
  p.bfc   = (const float*)d_in[10];
  p.W2    = (const float*)d_in[11];
  p.b2    = (const float*)d_in[12];
  p.W3    = (const float*)d_in[13];
  p.b3    = (const float*)d_in[14];
  p.W4    = (const float*)d_in[15];
  p.b4    = (const float*)d_in[16];
  p.gbA   = (const float*)d_in[17];
  p.bbA   = (const float*)d_in[18];
  p.gbB   = (const float*)d_in[19];
  p.bbB   = (const float*)d_in[20];
  p.gbC   = (const float*)d_in[21];
  p.bbC   = (const float*)d_in[22];
  p.esrc  = (const int*)d_in[23];
  p.edst  = (const int*)d_in[24];
  p.n2g   = (const int*)d_in[25];
  p.out   = (float*)d_out;

  float* ws = (float*)d_ws;
  size_t off = 0;
  p.hb0 = (unsigned short*)(ws + off); off += (size_t)N_NODES*D/2;
  p.hb1 = (unsigned short*)(ws + off); off += (size_t)N_NODES*D/2;
  p.hb2 = (unsigned short*)(ws + off); off += (size_t)N_NODES*D/2;
  p.zbuf  = ws + off;                 // zero region start
  p.csum1 = ws + off; off += 512;
  p.csq1  = ws + off; off += 512;
  p.csum2 = ws + off; off += 512;
  p.csq2  = ws + off; off += 512;
  p.s1    = ws + off; off += 256;
  p.q1    = ws + off; off += 256;
  p.s2    = ws + off; off += 256;
  p.q2    = ws + off; off += 256;
  p.s3    = ws + off; off += 256;
  p.q3    = ws + off; off += 256;
  p.qemb  = ws + off; off += (size_t)B*D;   // end zero region (ZCOUNT floats total)
  p.G1   = ws + off; off += (size_t)NROW*DH;
  p.G2   = ws + off; off += (size_t)NROW*DH;
  p.G3   = ws + off; off += (size_t)NROW*DH;
  p.part = ws + off; off += (size_t)F1_NS*NROW*DH;
  p.degi     = (int*)(ws + off); off += N_NODES;
  p.rowstart = (int*)(ws + off); off += N_NODES + 1;
  p.cursor   = (int*)(ws + off); off += N_NODES;
  p.csr      = (int*)(ws + off); off += N_EDGES;
  p.gstart   = (int*)(ws + off); off += B + 1;

  k_setup<<<64, 256, 0, stream>>>(p);
  k_deg<<<(N_EDGES+255)/256, 256, 0, stream>>>(p);
  k_scan<<<1, 256, 0, stream>>>(p);
  k_init<<<IM_UNITS, 256, 0, stream>>>(p);
  k_fill<<<(N_EDGES+255)/256, 256, 0, stream>>>(p);
  k_g1<<<GBLOCKS, 256, 0, stream>>>(p);
  k_g2<<<GBLOCKS, 256, 0, stream>>>(p);
  k_readout<<<512, 256, 0, stream>>>(p);
  k_fc1<<<480, 256, 0, stream>>>(p);
  k_reduce<<<80, 256, 0, stream>>>(p);
  k_fc2<<<NROW, 256, 0, stream>>>(p);
  k_fc3<<<NROW, 256, 0, stream>>>(p);
  k_final<<<NROW/4, 256, 0, stream>>>(p);
}

// Round 10
// 252.937 us; speedup vs baseline: 3.0167x; 1.0094x over previous
//
#include <hip/hip_runtime.h>
#include <hip/hip_bf16.h>
#include <math.h>

#define N_NODES 10000
#define N_EDGES 160000
#define D 512
#define DIN 20
#define B 64
#define KC 10
#define DH 256
#define NROW (B*KC)   // 640
#define BN_EPS 1e-5f

#define ZCOUNT 36352            // csum1,csq1,csum2,csq2 (2048) + s1..q3 (1536) + qemb (32768)
#define Z4 (ZCOUNT/4)           // 9088
#define D4 (N_NODES/4)          // 2500
#define IM_ROWS 8
#define IM_UNITS (N_NODES/IM_ROWS)  // 1250
#define DEG_BLOCKS 625
#define GWAVES 4
#define GBLOCKS 1250            // 5000 waves, 2 nodes each
#define F1_NS 6
#define F1_ROWS 8
#define F1_KS 256

struct P {
  const float *x, *pg, *neigh, *Winit, *binit;
  const float *g1, *be1, *g2, *be2;
  const float *Wfc, *bfc, *W2, *b2, *W3, *b3, *W4, *b4;
  const float *gbA, *bbA, *gbB, *bbB, *gbC, *bbC;
  const int *esrc, *edst, *n2g;
  unsigned short *hb0, *hb1, *hb2;
  float *zbuf, *csum1, *csq1, *csum2, *csq2;
  float *s1,*q1,*s2,*q2,*s3,*q3, *qemb;
  float *G1,*G2,*G3,*part;
  int *degi,*rowstart,*cursor,*csr,*gstart;
  float *out;
};

__device__ __forceinline__ void f4acc(float4& a, const float4 v){
  a.x += v.x; a.y += v.y; a.z += v.z; a.w += v.w;
}
__device__ __forceinline__ void mk_affine(const float4 s, const float4 q, const float4 g,
                                          const float4 b, float4& sc, float4& sh){
  const float invN = 1.0f/(float)N_NODES;
  float mu, var, rs;
  mu = s.x*invN; var = q.x*invN - mu*mu; rs = rsqrtf(var+BN_EPS); sc.x = rs*g.x; sh.x = b.x - mu*sc.x;
  mu = s.y*invN; var = q.y*invN - mu*mu; rs = rsqrtf(var+BN_EPS); sc.y = rs*g.y; sh.y = b.y - mu*sc.y;
  mu = s.z*invN; var = q.z*invN - mu*mu; rs = rsqrtf(var+BN_EPS); sc.z = rs*g.z; sh.z = b.z - mu*sc.z;
  mu = s.w*invN; var = q.w*invN - mu*mu; rs = rsqrtf(var+BN_EPS); sc.w = rs*g.w; sh.w = b.w - mu*sc.w;
}
__device__ __forceinline__ float4 aff_relu(const float4 v, const float4 sc, const float4 sh){
  float4 o;
  o.x = fmaxf(fmaf(v.x, sc.x, sh.x), 0.0f);
  o.y = fmaxf(fmaf(v.y, sc.y, sh.y), 0.0f);
  o.z = fmaxf(fmaf(v.z, sc.z, sh.z), 0.0f);
  o.w = fmaxf(fmaf(v.w, sc.w, sh.w), 0.0f);
  return o;
}
__device__ __forceinline__ void bf_unpack(const uint4 u, float4& lo, float4& hi){
  lo.x = __uint_as_float(u.x << 16); lo.y = __uint_as_float(u.x & 0xffff0000u);
  lo.z = __uint_as_float(u.y << 16); lo.w = __uint_as_float(u.y & 0xffff0000u);
  hi.x = __uint_as_float(u.z << 16); hi.y = __uint_as_float(u.z & 0xffff0000u);
  hi.z = __uint_as_float(u.w << 16); hi.w = __uint_as_float(u.w & 0xffff0000u);
}
__device__ __forceinline__ unsigned bf_pack2(float a, float b){ // RNE
  unsigned ua = __float_as_uint(a); ua = (ua + 0x7fffu + ((ua>>16)&1u)) >> 16;
  unsigned ub = __float_as_uint(b); ub = (ub + 0x7fffu + ((ub>>16)&1u)) & 0xffff0000u;
  return (ua & 0xffffu) | ub;
}
__device__ __forceinline__ unsigned short bf_pack1(float a){
  unsigned ua = __float_as_uint(a); return (unsigned short)((ua + 0x7fffu + ((ua>>16)&1u)) >> 16);
}

// ================= pipelined gather machinery =================
struct Batch { uint4 v[8]; };

__device__ __forceinline__ void load8(Batch& b, const uint4* __restrict__ hb4,
                                      int idxreg, int k, int c, int lane){
  #pragma unroll
  for (int j = 0; j < 8; ++j){
    int r = k*8 + j;
    int ri = (r < c) ? r : (c-1);
    int idx = __builtin_amdgcn_readlane(idxreg, ri);
    b.v[j] = hb4[(size_t)idx*64 + lane];
  }
}

template<bool FUSED>
__device__ __forceinline__ void cons8(const Batch& b, int k, int c,
    float4& accLo, float4& accHi,
    const float4& scA, const float4& shA, const float4& scB, const float4& shB){
  #pragma unroll
  for (int j = 0; j < 8; ++j){
    int r = k*8 + j;
    float w = (r < c) ? 1.0f : 0.0f;
    float4 lo, hi; bf_unpack(b.v[j], lo, hi);
    if (FUSED){ lo = aff_relu(lo, scA, shA); hi = aff_relu(hi, scB, shB); }
    accLo.x = fmaf(lo.x, w, accLo.x); accLo.y = fmaf(lo.y, w, accLo.y);
    accLo.z = fmaf(lo.z, w, accLo.z); accLo.w = fmaf(lo.w, w, accLo.w);
    accHi.x = fmaf(hi.x, w, accHi.x); accHi.y = fmaf(hi.y, w, accHi.y);
    accHi.z = fmaf(hi.z, w, accHi.z); accHi.w = fmaf(hi.w, w, accHi.w);
  }
}

template<bool FUSED>
__device__ __forceinline__ void gather_body(const P& p,
    const unsigned short* __restrict__ hin, unsigned short* __restrict__ hout,
    const float* pcs, const float* pcq, const float* pgm, const float* pbt,
    float* cs, float* cq, float* red){
  int t = threadIdx.x;
  int lane = t & 63;
  int wave = t >> 6;
  int wid  = blockIdx.x*GWAVES + wave;   // 0..4999
  int nA = 2*wid, nB = nA + 1;
  const uint4* hb4 = (const uint4*)hin;
  // self rows: issue earliest, consumed last
  uint4 uSA = hb4[(size_t)nA*64 + lane];
  uint4 uSB = hb4[(size_t)nB*64 + lane];
  float4 scA, shA, scB, shB;
  if (FUSED){
    mk_affine(((const float4*)pcs)[2*lane],   ((const float4*)pcq)[2*lane],
              ((const float4*)pgm)[2*lane],   ((const float4*)pbt)[2*lane],   scA, shA);
    mk_affine(((const float4*)pcs)[2*lane+1], ((const float4*)pcq)[2*lane+1],
              ((const float4*)pgm)[2*lane+1], ((const float4*)pbt)[2*lane+1], scB, shB);
  }
  int sA = p.rowstart[nA], sB = p.rowstart[nB], eB = p.rowstart[nB+1];
  int cA = sB - sA, cB = eB - sB;
  int idxA = (lane < cA) ? p.csr[sA + lane] : 0;
  int idxB = (lane < cB) ? p.csr[sB + lane] : 0;
  int cAf = (cA > 64) ? 64 : cA;
  int cBf = (cB > 64) ? 64 : cB;
  int bA = (cAf + 7) >> 3, bB = (cBf + 7) >> 3;
  Batch A0, A1, B0, B1;
  if (bA > 0) load8(A0, hb4, idxA, 0, cAf, lane);
  if (bB > 0) load8(B0, hb4, idxB, 0, cBf, lane);
  if (bA > 1) load8(A1, hb4, idxA, 1, cAf, lane);
  if (bB > 1) load8(B1, hb4, idxB, 1, cBf, lane);
  float4 aLoA = make_float4(0,0,0,0), aHiA = make_float4(0,0,0,0);
  float4 aLoB = make_float4(0,0,0,0), aHiB = make_float4(0,0,0,0);
  int ta = 0, tb = 0;
  while (ta < bA || tb < bB){
    if (ta < bA){ cons8<FUSED>(A0, ta, cAf, aLoA, aHiA, scA, shA, scB, shB);
                  if (ta+2 < bA) load8(A0, hb4, idxA, ta+2, cAf, lane); ta++; }
    if (tb < bB){ cons8<FUSED>(B0, tb, cBf, aLoB, aHiB, scA, shA, scB, shB);
                  if (tb+2 < bB) load8(B0, hb4, idxB, tb+2, cBf, lane); tb++; }
    if (ta < bA){ cons8<FUSED>(A1, ta, cAf, aLoA, aHiA, scA, shA, scB, shB);
                  if (ta+2 < bA) load8(A1, hb4, idxA, ta+2, cAf, lane); ta++; }
    if (tb < bB){ cons8<FUSED>(B1, tb, cBf, aLoB, aHiB, scA, shA, scB, shB);
                  if (tb+2 < bB) load8(B1, hb4, idxB, tb+2, cBf, lane); tb++; }
  }
  // rare tails: degree > 64 (statistically absent for this graph, kept for correctness)
  for (int base = 64; base < cA; base += 64){
    int cnt = cA - base; if (cnt > 64) cnt = 64;
    int mi = (lane < cnt) ? p.csr[sA + base + lane] : 0;
    for (int j = 0; j < cnt; ++j){
      int idx = __builtin_amdgcn_readlane(mi, j);
      uint4 u = hb4[(size_t)idx*64 + lane];
      float4 lo, hi; bf_unpack(u, lo, hi);
      if (FUSED){ lo = aff_relu(lo, scA, shA); hi = aff_relu(hi, scB, shB); }
      f4acc(aLoA, lo); f4acc(aHiA, hi);
    }
  }
  for (int base = 64; base < cB; base += 64){
    int cnt = cB - base; if (cnt > 64) cnt = 64;
    int mi = (lane < cnt) ? p.csr[sB + base + lane] : 0;
    for (int j = 0; j < cnt; ++j){
      int idx = __builtin_amdgcn_readlane(mi, j);
      uint4 u = hb4[(size_t)idx*64 + lane];
      float4 lo, hi; bf_unpack(u, lo, hi);
      if (FUSED){ lo = aff_relu(lo, scA, shA); hi = aff_relu(hi, scB, shB); }
      f4acc(aLoB, lo); f4acc(aHiB, hi);
    }
  }
  // finalize both nodes + stats
  float4 sLo = make_float4(0,0,0,0), sHi = make_float4(0,0,0,0);
  float4 qLo = make_float4(0,0,0,0), qHi = make_float4(0,0,0,0);
  #pragma unroll
  for (int n = 0; n < 2; ++n){
    int node = (n == 0) ? nA : nB;
    int cnt  = (n == 0) ? cA : cB;
    uint4 us = (n == 0) ? uSA : uSB;
    float4 sumLo = (n == 0) ? aLoA : aLoB;
    float4 sumHi = (n == 0) ? aHiA : aHiB;
    float inv = 1.0f/fmaxf((float)cnt, 1.0f);
    float4 hLo, hHi; bf_unpack(us, hLo, hHi);
    if (FUSED){ hLo = aff_relu(hLo, scA, shA); hHi = aff_relu(hHi, scB, shB); }
    float4 oLo, oHi;
    oLo.x = hLo.x + sumLo.x*inv;  oLo.y = hLo.y + sumLo.y*inv;
    oLo.z = hLo.z + sumLo.z*inv;  oLo.w = hLo.w + sumLo.w*inv;
    oHi.x = hHi.x + sumHi.x*inv;  oHi.y = hHi.y + sumHi.y*inv;
    oHi.z = hHi.z + sumHi.z*inv;  oHi.w = hHi.w + sumHi.w*inv;
    uint4 ou;
    ou.x = bf_pack2(oLo.x, oLo.y); ou.y = bf_pack2(oLo.z, oLo.w);
    ou.z = bf_pack2(oHi.x, oHi.y); ou.w = bf_pack2(oHi.z, oHi.w);
    ((uint4*)hout)[(size_t)node*64 + lane] = ou;
    f4acc(sLo, oLo); f4acc(sHi, oHi);
    qLo.x += oLo.x*oLo.x; qLo.y += oLo.y*oLo.y; qLo.z += oLo.z*oLo.z; qLo.w += oLo.w*oLo.w;
    qHi.x += oHi.x*oHi.x; qHi.y += oHi.y*oHi.y; qHi.z += oHi.z*oHi.z; qHi.w += oHi.w*oHi.w;
  }
  float* my = red + wave*1024;
  int c = 8*lane;
  *((float4*)&my[c])      = sLo;  *((float4*)&my[c+4])     = sHi;
  *((float4*)&my[512+c])  = qLo;  *((float4*)&my[512+c+4]) = qHi;
  __syncthreads();
  for (int e = t; e < 1024; e += 256){
    float v = red[e] + red[1024+e] + red[2048+e] + red[3072+e];
    if (e < 512) atomicAdd(&cs[e], v);
    else         atomicAdd(&cq[e-512], v);
  }
}

// ================= kernels =================
__global__ __launch_bounds__(256) void k_setup(P p){
  int b = blockIdx.x, nb = gridDim.x, t = threadIdx.x;
  for (int i4 = b*256 + t; i4 < Z4 + D4; i4 += nb*256){
    if (i4 < Z4) ((float4*)p.zbuf)[i4] = make_float4(0.f,0.f,0.f,0.f);
    else         ((int4*)p.degi)[i4 - Z4] = make_int4(0,0,0,0);
  }
  if (b == 0 && t <= B){
    int lo = 0, hi = N_NODES;
    while (lo < hi){ int mid = (lo+hi)>>1; if (p.n2g[mid] < t) lo = mid+1; else hi = mid; }
    p.gstart[t] = lo;
  }
}

// fused: blocks [0,625) histogram degrees; blocks [625,1875) do init projection
__global__ __launch_bounds__(256) void k_deg_init(P p){
  __shared__ float xs[IM_ROWS*DIN];
  int t = threadIdx.x;
  if (blockIdx.x < DEG_BLOCKS){
    int e = blockIdx.x*256 + t;
    if (e < N_EDGES) atomicAdd(&p.degi[p.edst[e]], 1);
    return;
  }
  int unit = blockIdx.x - DEG_BLOCKS;   // 0..1249
  float wlo[DIN], whi[DIN];
  #pragma unroll
  for (int k = 0; k < DIN; ++k){ wlo[k] = p.Winit[k*D + t]; whi[k] = p.Winit[k*D + t + 256]; }
  float b0 = p.binit[t], b1 = p.binit[t+256];
  int r0 = unit*IM_ROWS;
  for (int i = t; i < IM_ROWS*DIN; i += 256) xs[i] = p.x[(size_t)r0*DIN + i];
  __syncthreads();
  for (int rr = 0; rr < IM_ROWS; ++rr){
    float a0 = b0, a1 = b1;
    #pragma unroll
    for (int k = 0; k < DIN; ++k){
      float xv = xs[rr*DIN + k];
      a0 += xv*wlo[k]; a1 += xv*whi[k];
    }
    p.hb0[(size_t)(r0+rr)*D + t]       = bf_pack1(a0);
    p.hb0[(size_t)(r0+rr)*D + t + 256] = bf_pack1(a1);
  }
}

__global__ __launch_bounds__(256) void k_scan(P p){
  __shared__ int part[256];
  int t = threadIdx.x;
  const int PER = (N_NODES + 255)/256; // 40
  int base = t*PER;
  int s = 0;
  for (int i = 0; i < PER; ++i){ int idx = base+i; if (idx < N_NODES) s += p.degi[idx]; }
  part[t] = s;
  __syncthreads();
  for (int off = 1; off < 256; off <<= 1){
    int v = (t >= off) ? part[t-off] : 0;
    __syncthreads();
    part[t] += v;
    __syncthreads();
  }
  int run = (t > 0) ? part[t-1] : 0;
  for (int i = 0; i < PER; ++i){
    int idx = base+i;
    if (idx < N_NODES){ p.rowstart[idx] = run; p.cursor[idx] = run; run += p.degi[idx]; }
  }
  if (t == 255) p.rowstart[N_NODES] = run;
}

__global__ __launch_bounds__(256) void k_fill(P p){
  int e = blockIdx.x*256 + threadIdx.x;
  if (e < N_EDGES){
    int pos = atomicAdd(&p.cursor[p.edst[e]], 1);
    p.csr[pos] = p.esrc[e];
  }
}

__global__ __launch_bounds__(256) void k_g1(P p){
  __shared__ float red[4096];
  gather_body<false>(p, p.hb0, p.hb1, nullptr,nullptr,nullptr,nullptr, p.csum1, p.csq1, red);
}
__global__ __launch_bounds__(256) void k_g2(P p){
  __shared__ float red[4096];
  gather_body<true>(p, p.hb1, p.hb2, p.csum1, p.csq1, p.g1, p.be1, p.csum2, p.csq2, red);
}

__global__ __launch_bounds__(256) void k_readout(P p){
  __shared__ float red[2048];
  int g = blockIdx.x >> 3, chunk = blockIdx.x & 7;
  int t = threadIdx.x;
  int lane = t & 63, wave = t >> 6;
  const uint4* hb4 = (const uint4*)p.hb2;
  float4 scA, shA, scB, shB;
  mk_affine(((const float4*)p.csum2)[2*lane],   ((const float4*)p.csq2)[2*lane],
            ((const float4*)p.g2)[2*lane],      ((const float4*)p.be2)[2*lane],   scA, shA);
  mk_affine(((const float4*)p.csum2)[2*lane+1], ((const float4*)p.csq2)[2*lane+1],
            ((const float4*)p.g2)[2*lane+1],    ((const float4*)p.be2)[2*lane+1], scB, shB);
  int s = p.gstart[g], e = p.gstart[g+1];
  int rows = e - s;
  int per = (rows + 7)/8;
  int r0 = s + chunk*per;
  int r1 = r0 + per; if (r1 > e) r1 = e;
  float4 aLo = make_float4(0,0,0,0), aHi = make_float4(0,0,0,0);
  for (int r = r0 + wave; r < r1; r += 4){
    uint4 u = hb4[(size_t)r*64 + lane];
    float4 lo, hi; bf_unpack(u, lo, hi);
    lo = aff_relu(lo, scA, shA); hi = aff_relu(hi, scB, shB);
    f4acc(aLo, lo); f4acc(aHi, hi);
  }
  int c = 8*lane;
  *((float4*)&red[wave*512 + c])     = aLo;
  *((float4*)&red[wave*512 + c + 4]) = aHi;
  __syncthreads();
  for (int e2 = t; e2 < 512; e2 += 256){
    float v = red[e2] + red[512+e2] + red[1024+e2] + red[1536+e2];
    atomicAdd(&p.qemb[(size_t)g*D + e2], v);
  }
}

__global__ __launch_bounds__(256) void k_fc1(P p){
  __shared__ float brow[F1_ROWS*F1_KS];
  int t = threadIdx.x;
  int rb = blockIdx.x % 80, ks = blockIdx.x / 80;
  int r0 = rb*F1_ROWS, k0 = ks*F1_KS;
  for (int rr = 0; rr < F1_ROWS; ++rr){
    int r = r0+rr;
    int g = r/KC, k = r - g*KC;
    int j = k0 + t;
    float v;
    if (j < D){
      float invc = 1.0f/fmaxf((float)(p.gstart[g+1]-p.gstart[g]), 1.0f);
      v = p.qemb[(size_t)g*D + j]*invc;
    } else if (j < 2*D){
      v = p.pg[(size_t)g*D + (j-D)];
    } else {
      v = p.neigh[((size_t)g*KC + k)*D + (j-2*D)];
    }
    brow[rr*F1_KS + t] = v;
  }
  __syncthreads();
  float acc[F1_ROWS] = {0.f,0.f,0.f,0.f,0.f,0.f,0.f,0.f};
  #pragma unroll 4
  for (int kk = 0; kk < F1_KS; ++kk){
    float w = p.Wfc[(size_t)(k0+kk)*DH + t];
    #pragma unroll
    for (int rr = 0; rr < F1_ROWS; ++rr) acc[rr] += brow[rr*F1_KS + kk]*w;
  }
  for (int rr = 0; rr < F1_ROWS; ++rr)
    p.part[((size_t)ks*NROW + r0+rr)*DH + t] = acc[rr];
}

__global__ __launch_bounds__(256) void k_reduce(P p){
  int t = threadIdx.x;
  int r0 = blockIdx.x*8;
  float bval = p.bfc[t];
  float ls = 0.f, lq = 0.f;
  for (int rr = 0; rr < 8; ++rr){
    int r = r0+rr;
    float acc = bval;
    for (int sl = 0; sl < F1_NS; ++sl) acc += p.part[((size_t)sl*NROW + r)*DH + t];
    p.G1[(size_t)r*DH + t] = acc;
    ls += acc; lq += acc*acc;
  }
  atomicAdd(&p.s1[t], ls); atomicAdd(&p.q1[t], lq);
}

__device__ __forceinline__ void fcmid_body(const float* in, const float* ps, const float* pq,
    const float* gamma, const float* beta, const float* W, const float* bias,
    float* outG, float* s, float* q, float* row){
  int t = threadIdx.x;
  int r = blockIdx.x;
  const float invM = 1.0f/(float)NROW;
  {
    float mu = ps[t]*invM;
    float var = pq[t]*invM - mu*mu;
    float rs = rsqrtf(var + BN_EPS);
    float v = in[(size_t)r*DH + t];
    row[t] = fmaxf((v-mu)*rs*gamma[t] + beta[t], 0.0f);
  }
  __syncthreads();
  float acc = bias[t];
  #pragma unroll 8
  for (int kk = 0; kk < DH; ++kk)
    acc += row[kk]*W[(size_t)kk*DH + t];
  outG[(size_t)r*DH + t] = acc;
  atomicAdd(&s[t], acc); atomicAdd(&q[t], acc*acc);
}
__global__ __launch_bounds__(256) void k_fc2(P p){ __shared__ float row[DH];
  fcmid_body(p.G1, p.s1, p.q1, p.gbA, p.bbA, p.W2, p.b2, p.G2, p.s2, p.q2, row); }
__global__ __launch_bounds__(256) void k_fc3(P p){ __shared__ float row[DH];
  fcmid_body(p.G2, p.s2, p.q2, p.gbB, p.bbB, p.W3, p.b3, p.G3, p.s3, p.q3, row); }

__global__ __launch_bounds__(256) void k_final(P p){
  int t = threadIdx.x;
  int wave = t>>6, lane = t&63;
  int r = blockIdx.x*4 + wave;
  const float invM = 1.0f/(float)NROW;
  float sum = 0.f;
  #pragma unroll
  for (int j = 0; j < 4; ++j){
    int c = lane + 64*j;
    float mu = p.s3[c]*invM;
    float var = p.q3[c]*invM - mu*mu;
    float rs = rsqrtf(var+BN_EPS);
    float v = p.G3[(size_t)r*DH + c];
    v = fmaxf((v-mu)*rs*p.gbC[c] + p.bbC[c], 0.0f);
    sum += v*p.W4[c];
  }
  #pragma unroll
  for (int off = 32; off > 0; off >>= 1) sum += __shfl_down(sum, off, 64);
  if (lane == 0){
    float z = sum + p.b4[0];
    p.out[r] = 1.0f/(1.0f + expf(-z));
  }
}

extern "C" void kernel_launch(void* const* d_in, const int* in_sizes, int n_in,
                              void* d_out, int out_size, void* d_ws, size_t ws_size,
                              hipStream_t stream) {
  P p;
  p.x     = (const float*)d_in[0];
  p.pg    = (const float*)d_in[1];
  p.neigh = (const float*)d_in[2];
  p.Winit = (const float*)d_in[3];
  p.binit = (const float*)d_in[4];
  p.g1    = (const float*)d_in[5];
  p.be1   = (const float*)d_in[6];
  p.g2    = (const float*)d_in[7];
  p.be2   = (const float*)d_in[8];
  p.Wfc   = (const float*)d_in[9];
  p.bfc   = (const float*)d_in[10];
  p.W2    = (const float*)d_in[11];
  p.b2    = (const float*)d_in[12];
  p.W3    = (const float*)d_in[13];
  p.b3    = (const float*)d_in[14];
  p.W4    = (const float*)d_in[15];
  p.b4    = (const float*)d_in[16];
  p.gbA   = (const float*)d_in[17];
  p.bbA   = (const float*)d_in[18];
  p.gbB   = (const float*)d_in[19];
  p.bbB   = (const float*)d_in[20];
  p.gbC   = (const float*)d_in[21];
  p.bbC   = (const float*)d_in[22];
  p.esrc  = (const int*)d_in[23];
  p.edst  = (const int*)d_in[24];
  p.n2g   = (const int*)d_in[25];
  p.out   = (float*)d_out;

  float* ws = (float*)d_ws;
  size_t off = 0;
  p.hb0 = (unsigned short*)(ws + off); off += (size_t)N_NODES*D/2;
  p.hb1 = (unsigned short*)(ws + off); off += (size_t)N_NODES*D/2;
  p.hb2 = (unsigned short*)(ws + off); off += (size_t)N_NODES*D/2;
  p.zbuf  = ws + off;                 // zero region start
  p.csum1 = ws + off; off += 512;
  p.csq1  = ws + off; off += 512;
  p.csum2 = ws + off; off += 512;
  p.csq2  = ws + off; off += 512;
  p.s1    = ws + off; off += 256;
  p.q1    = ws + off; off += 256;
  p.s2    = ws + off; off += 256;
  p.q2    = ws + off; off += 256;
  p.s3    = ws + off; off += 256;
  p.q3    = ws + off; off += 256;
  p.qemb  = ws + off; off += (size_t)B*D;   // end zero region (ZCOUNT floats total)
  p.G1   = ws + off; off += (size_t)NROW*DH;
  p.G2   = ws + off; off += (size_t)NROW*DH;
  p.G3   = ws + off; off += (size_t)NROW*DH;
  p.part = ws + off; off += (size_t)F1_NS*NROW*DH;
  p.degi     = (int*)(ws + off); off += N_NODES;
  p.rowstart = (int*)(ws + off); off += N_NODES + 1;
  p.cursor   = (int*)(ws + off); off += N_NODES;
  p.csr      = (int*)(ws + off); off += N_EDGES;
  p.gstart   = (int*)(ws + off); off += B + 1;

  k_setup<<<64, 256, 0, stream>>>(p);
  k_deg_init<<<DEG_BLOCKS + IM_UNITS, 256, 0, stream>>>(p);
  k_scan<<<1, 256, 0, stream>>>(p);
  k_fill<<<(N_EDGES+255)/256, 256, 0, stream>>>(p);
  k_g1<<<GBLOCKS, 256, 0, stream>>>(p);
  k_g2<<<GBLOCKS, 256, 0, stream>>>(p);
  k_readout<<<512, 256, 0, stream>>>(p);
  k_fc1<<<480, 256, 0, stream>>>(p);
  k_reduce<<<80, 256, 0, stream>>>(p);
  k_fc2<<<NROW, 256, 0, stream>>>(p);
  k_fc3<<<NROW, 256, 0, stream>>>(p);
  k_final<<<NROW/4, 256, 0, stream>>>(p);
}

// Round 11
// 240.491 us; speedup vs baseline: 3.1729x; 1.0518x over previous
//
#include <hip/hip_runtime.h>
#include <hip/hip_bf16.h>
#include <math.h>

#define N_NODES 10000
#define N_EDGES 160000
#define D 512
#define DIN 20
#define B 64
#define KC 10
#define DH 256
#define NROW (B*KC)   // 640
#define BN_EPS 1e-5f

#define ZCOUNT 36352            // csum1,csq1,csum2,csq2 (2048) + s1..q3 (1536) + qemb (32768)
#define Z4 (ZCOUNT/4)           // 9088
#define D4 (N_NODES/4)          // 2500
#define IM_ROWS 8
#define IM_UNITS (N_NODES/IM_ROWS)  // 1250
#define DEG_BLOCKS 625
#define GWAVES 4
#define GBLOCKS 1250            // 5000 waves, 2 nodes each
#define F1_NS 6
#define F1_ROWS 8
#define F1_KS 256
#define FM_ROWS 4
#define FM_KS 128
#define FM_NS 2

struct P {
  const float *x, *pg, *neigh, *Winit, *binit;
  const float *g1, *be1, *g2, *be2;
  const float *Wfc, *bfc, *W2, *b2, *W3, *b3, *W4, *b4;
  const float *gbA, *bbA, *gbB, *bbB, *gbC, *bbC;
  const int *esrc, *edst, *n2g;
  unsigned short *hb0, *hb1, *hb2;
  float *zbuf, *csum1, *csq1, *csum2, *csq2;
  float *s1,*q1,*s2,*q2,*s3,*q3, *qemb;
  float *G1,*G2,*G3,*part;
  int *degi,*rowstart,*cursor,*csr,*gstart;
  float *out;
};

__device__ __forceinline__ void f4acc(float4& a, const float4 v){
  a.x += v.x; a.y += v.y; a.z += v.z; a.w += v.w;
}
__device__ __forceinline__ void mk_affine(const float4 s, const float4 q, const float4 g,
                                          const float4 b, float4& sc, float4& sh){
  const float invN = 1.0f/(float)N_NODES;
  float mu, var, rs;
  mu = s.x*invN; var = q.x*invN - mu*mu; rs = rsqrtf(var+BN_EPS); sc.x = rs*g.x; sh.x = b.x - mu*sc.x;
  mu = s.y*invN; var = q.y*invN - mu*mu; rs = rsqrtf(var+BN_EPS); sc.y = rs*g.y; sh.y = b.y - mu*sc.y;
  mu = s.z*invN; var = q.z*invN - mu*mu; rs = rsqrtf(var+BN_EPS); sc.z = rs*g.z; sh.z = b.z - mu*sc.z;
  mu = s.w*invN; var = q.w*invN - mu*mu; rs = rsqrtf(var+BN_EPS); sc.w = rs*g.w; sh.w = b.w - mu*sc.w;
}
__device__ __forceinline__ float4 aff_relu(const float4 v, const float4 sc, const float4 sh){
  float4 o;
  o.x = fmaxf(fmaf(v.x, sc.x, sh.x), 0.0f);
  o.y = fmaxf(fmaf(v.y, sc.y, sh.y), 0.0f);
  o.z = fmaxf(fmaf(v.z, sc.z, sh.z), 0.0f);
  o.w = fmaxf(fmaf(v.w, sc.w, sh.w), 0.0f);
  return o;
}
__device__ __forceinline__ void bf_unpack(const uint4 u, float4& lo, float4& hi){
  lo.x = __uint_as_float(u.x << 16); lo.y = __uint_as_float(u.x & 0xffff0000u);
  lo.z = __uint_as_float(u.y << 16); lo.w = __uint_as_float(u.y & 0xffff0000u);
  hi.x = __uint_as_float(u.z << 16); hi.y = __uint_as_float(u.z & 0xffff0000u);
  hi.z = __uint_as_float(u.w << 16); hi.w = __uint_as_float(u.w & 0xffff0000u);
}
__device__ __forceinline__ unsigned bf_pack2(float a, float b){ // RNE
  unsigned ua = __float_as_uint(a); ua = (ua + 0x7fffu + ((ua>>16)&1u)) >> 16;
  unsigned ub = __float_as_uint(b); ub = (ub + 0x7fffu + ((ub>>16)&1u)) & 0xffff0000u;
  return (ua & 0xffffu) | ub;
}
__device__ __forceinline__ unsigned short bf_pack1(float a){
  unsigned ua = __float_as_uint(a); return (unsigned short)((ua + 0x7fffu + ((ua>>16)&1u)) >> 16);
}

// ================= gather (round-9 proven form: batch-8, shfl broadcast) =================
template<bool FUSED>
__device__ __forceinline__ void gather_body(const P& p,
    const unsigned short* __restrict__ hin, unsigned short* __restrict__ hout,
    const float* pcs, const float* pcq, const float* pgm, const float* pbt,
    float* cs, float* cq, float* red){
  int t = threadIdx.x;
  int lane = t & 63;
  int wave = t >> 6;
  int wid  = blockIdx.x*GWAVES + wave;
  int tot  = gridDim.x*GWAVES;
  const uint4* hb4 = (const uint4*)hin;   // row stride = 64 uint4
  float4 scA, shA, scB, shB;
  if (FUSED){
    mk_affine(((const float4*)pcs)[2*lane],   ((const float4*)pcq)[2*lane],
              ((const float4*)pgm)[2*lane],   ((const float4*)pbt)[2*lane],   scA, shA);
    mk_affine(((const float4*)pcs)[2*lane+1], ((const float4*)pcq)[2*lane+1],
              ((const float4*)pgm)[2*lane+1], ((const float4*)pbt)[2*lane+1], scB, shB);
  }
  float4 sLo = make_float4(0,0,0,0), sHi = make_float4(0,0,0,0);
  float4 qLo = make_float4(0,0,0,0), qHi = make_float4(0,0,0,0);
  for (int node = wid; node < N_NODES; node += tot){
    int start = p.rowstart[node], end = p.rowstart[node+1];
    float4 aLo = make_float4(0,0,0,0), aHi = make_float4(0,0,0,0);
    float4 bLo = make_float4(0,0,0,0), bHi = make_float4(0,0,0,0);
    for (int base = start; base < end; base += 64){
      int cnt = end - base; if (cnt > 64) cnt = 64;
      int myidx = (lane < cnt) ? p.csr[base+lane] : 0;
      int j = 0;
      for (; j+8 <= cnt; j += 8){
        uint4 u[8];
        #pragma unroll
        for (int k = 0; k < 8; ++k){
          int idx = __shfl(myidx, j+k, 64);
          u[k] = hb4[(size_t)idx*64 + lane];
        }
        #pragma unroll
        for (int k = 0; k < 8; ++k){
          float4 lo, hi; bf_unpack(u[k], lo, hi);
          if (FUSED){ lo = aff_relu(lo, scA, shA); hi = aff_relu(hi, scB, shB); }
          if (k & 1){ f4acc(bLo, lo); f4acc(bHi, hi); }
          else      { f4acc(aLo, lo); f4acc(aHi, hi); }
        }
      }
      for (; j < cnt; ++j){
        int idx = __shfl(myidx, j, 64);
        uint4 u0 = hb4[(size_t)idx*64 + lane];
        float4 lo, hi; bf_unpack(u0, lo, hi);
        if (FUSED){ lo = aff_relu(lo, scA, shA); hi = aff_relu(hi, scB, shB); }
        f4acc(aLo, lo); f4acc(aHi, hi);
      }
    }
    float inv = 1.0f/fmaxf((float)(end-start), 1.0f);
    uint4 us = hb4[(size_t)node*64 + lane];
    float4 hLo, hHi; bf_unpack(us, hLo, hHi);
    if (FUSED){ hLo = aff_relu(hLo, scA, shA); hHi = aff_relu(hHi, scB, shB); }
    float4 oLo, oHi;
    oLo.x = hLo.x + (aLo.x+bLo.x)*inv;  oLo.y = hLo.y + (aLo.y+bLo.y)*inv;
    oLo.z = hLo.z + (aLo.z+bLo.z)*inv;  oLo.w = hLo.w + (aLo.w+bLo.w)*inv;
    oHi.x = hHi.x + (aHi.x+bHi.x)*inv;  oHi.y = hHi.y + (aHi.y+bHi.y)*inv;
    oHi.z = hHi.z + (aHi.z+bHi.z)*inv;  oHi.w = hHi.w + (aHi.w+bHi.w)*inv;
    uint4 ou;
    ou.x = bf_pack2(oLo.x, oLo.y); ou.y = bf_pack2(oLo.z, oLo.w);
    ou.z = bf_pack2(oHi.x, oHi.y); ou.w = bf_pack2(oHi.z, oHi.w);
    ((uint4*)hout)[(size_t)node*64 + lane] = ou;
    f4acc(sLo, oLo); f4acc(sHi, oHi);
    qLo.x += oLo.x*oLo.x; qLo.y += oLo.y*oLo.y; qLo.z += oLo.z*oLo.z; qLo.w += oLo.w*oLo.w;
    qHi.x += oHi.x*oHi.x; qHi.y += oHi.y*oHi.y; qHi.z += oHi.z*oHi.z; qHi.w += oHi.w*oHi.w;
  }
  float* my = red + wave*1024;
  int c = 8*lane;
  *((float4*)&my[c])      = sLo;  *((float4*)&my[c+4])     = sHi;
  *((float4*)&my[512+c])  = qLo;  *((float4*)&my[512+c+4]) = qHi;
  __syncthreads();
  for (int e = t; e < 1024; e += 256){
    float v = red[e] + red[1024+e] + red[2048+e] + red[3072+e];
    if (e < 512) atomicAdd(&cs[e], v);
    else         atomicAdd(&cq[e-512], v);
  }
}

// ================= kernels =================
__global__ __launch_bounds__(256) void k_setup(P p){
  int b = blockIdx.x, nb = gridDim.x, t = threadIdx.x;
  for (int i4 = b*256 + t; i4 < Z4 + D4; i4 += nb*256){
    if (i4 < Z4) ((float4*)p.zbuf)[i4] = make_float4(0.f,0.f,0.f,0.f);
    else         ((int4*)p.degi)[i4 - Z4] = make_int4(0,0,0,0);
  }
  if (b == 0 && t <= B){
    int lo = 0, hi = N_NODES;
    while (lo < hi){ int mid = (lo+hi)>>1; if (p.n2g[mid] < t) lo = mid+1; else hi = mid; }
    p.gstart[t] = lo;
  }
}

// fused: blocks [0,625) degree histogram; blocks [625,1875) init projection (W in regs)
__global__ __launch_bounds__(256) void k_deg_init(P p){
  __shared__ float xs[IM_ROWS*DIN];
  int t = threadIdx.x;
  if (blockIdx.x < DEG_BLOCKS){
    int e = blockIdx.x*256 + t;
    if (e < N_EDGES) atomicAdd(&p.degi[p.edst[e]], 1);
    return;
  }
  int unit = blockIdx.x - DEG_BLOCKS;   // 0..1249
  float wlo[DIN], whi[DIN];
  #pragma unroll
  for (int k = 0; k < DIN; ++k){ wlo[k] = p.Winit[k*D + t]; whi[k] = p.Winit[k*D + t + 256]; }
  float b0 = p.binit[t], b1 = p.binit[t+256];
  int r0 = unit*IM_ROWS;
  for (int i = t; i < IM_ROWS*DIN; i += 256) xs[i] = p.x[(size_t)r0*DIN + i];
  __syncthreads();
  for (int rr = 0; rr < IM_ROWS; ++rr){
    float a0 = b0, a1 = b1;
    #pragma unroll
    for (int k = 0; k < DIN; ++k){
      float xv = xs[rr*DIN + k];
      a0 += xv*wlo[k]; a1 += xv*whi[k];
    }
    p.hb0[(size_t)(r0+rr)*D + t]       = bf_pack1(a0);
    p.hb0[(size_t)(r0+rr)*D + t + 256] = bf_pack1(a1);
  }
}

__global__ __launch_bounds__(256) void k_scan(P p){
  __shared__ int part[256];
  int t = threadIdx.x;
  const int PER = (N_NODES + 255)/256; // 40
  int base = t*PER;
  int s = 0;
  for (int i = 0; i < PER; ++i){ int idx = base+i; if (idx < N_NODES) s += p.degi[idx]; }
  part[t] = s;
  __syncthreads();
  for (int off = 1; off < 256; off <<= 1){
    int v = (t >= off) ? part[t-off] : 0;
    __syncthreads();
    part[t] += v;
    __syncthreads();
  }
  int run = (t > 0) ? part[t-1] : 0;
  for (int i = 0; i < PER; ++i){
    int idx = base+i;
    if (idx < N_NODES){ p.rowstart[idx] = run; p.cursor[idx] = run; run += p.degi[idx]; }
  }
  if (t == 255) p.rowstart[N_NODES] = run;
}

__global__ __launch_bounds__(256) void k_fill(P p){
  int e = blockIdx.x*256 + threadIdx.x;
  if (e < N_EDGES){
    int pos = atomicAdd(&p.cursor[p.edst[e]], 1);
    p.csr[pos] = p.esrc[e];
  }
}

__global__ __launch_bounds__(256) void k_g1(P p){
  __shared__ float red[4096];
  gather_body<false>(p, p.hb0, p.hb1, nullptr,nullptr,nullptr,nullptr, p.csum1, p.csq1, red);
}
__global__ __launch_bounds__(256) void k_g2(P p){
  __shared__ float red[4096];
  gather_body<true>(p, p.hb1, p.hb2, p.csum1, p.csq1, p.g1, p.be1, p.csum2, p.csq2, red);
}

__global__ __launch_bounds__(256) void k_readout(P p){
  __shared__ float red[2048];
  int g = blockIdx.x >> 3, chunk = blockIdx.x & 7;
  int t = threadIdx.x;
  int lane = t & 63, wave = t >> 6;
  const uint4* hb4 = (const uint4*)p.hb2;
  float4 scA, shA, scB, shB;
  mk_affine(((const float4*)p.csum2)[2*lane],   ((const float4*)p.csq2)[2*lane],
            ((const float4*)p.g2)[2*lane],      ((const float4*)p.be2)[2*lane],   scA, shA);
  mk_affine(((const float4*)p.csum2)[2*lane+1], ((const float4*)p.csq2)[2*lane+1],
            ((const float4*)p.g2)[2*lane+1],    ((const float4*)p.be2)[2*lane+1], scB, shB);
  int s = p.gstart[g], e = p.gstart[g+1];
  int rows = e - s;
  int per = (rows + 7)/8;
  int r0 = s + chunk*per;
  int r1 = r0 + per; if (r1 > e) r1 = e;
  float4 aLo = make_float4(0,0,0,0), aHi = make_float4(0,0,0,0);
  for (int r = r0 + wave; r < r1; r += 4){
    uint4 u = hb4[(size_t)r*64 + lane];
    float4 lo, hi; bf_unpack(u, lo, hi);
    lo = aff_relu(lo, scA, shA); hi = aff_relu(hi, scB, shB);
    f4acc(aLo, lo); f4acc(aHi, hi);
  }
  int c = 8*lane;
  *((float4*)&red[wave*512 + c])     = aLo;
  *((float4*)&red[wave*512 + c + 4]) = aHi;
  __syncthreads();
  for (int e2 = t; e2 < 512; e2 += 256){
    float v = red[e2] + red[512+e2] + red[1024+e2] + red[1536+e2];
    atomicAdd(&p.qemb[(size_t)g*D + e2], v);
  }
}

// ---- FC1 partials: [640,1536]@[1536,256], K split 6x256 (round-6 proven) ----
__global__ __launch_bounds__(256) void k_fc1(P p){
  __shared__ float brow[F1_ROWS*F1_KS];
  int t = threadIdx.x;
  int rb = blockIdx.x % 80, ks = blockIdx.x / 80;
  int r0 = rb*F1_ROWS, k0 = ks*F1_KS;
  for (int rr = 0; rr < F1_ROWS; ++rr){
    int r = r0+rr;
    int g = r/KC, k = r - g*KC;
    int j = k0 + t;
    float v;
    if (j < D){
      float invc = 1.0f/fmaxf((float)(p.gstart[g+1]-p.gstart[g]), 1.0f);
      v = p.qemb[(size_t)g*D + j]*invc;
    } else if (j < 2*D){
      v = p.pg[(size_t)g*D + (j-D)];
    } else {
      v = p.neigh[((size_t)g*KC + k)*D + (j-2*D)];
    }
    brow[rr*F1_KS + t] = v;
  }
  __syncthreads();
  float acc[F1_ROWS] = {0.f,0.f,0.f,0.f,0.f,0.f,0.f,0.f};
  #pragma unroll 4
  for (int kk = 0; kk < F1_KS; ++kk){
    float w = p.Wfc[(size_t)(k0+kk)*DH + t];
    #pragma unroll
    for (int rr = 0; rr < F1_ROWS; ++rr) acc[rr] += brow[rr*F1_KS + kk]*w;
  }
  for (int rr = 0; rr < F1_ROWS; ++rr)
    p.part[((size_t)ks*NROW + r0+rr)*DH + t] = acc[rr];
}

// ---- reduce partials + bias, write out, accumulate BN stats (nslice-parametric) ----
__global__ __launch_bounds__(256) void k_reduce(P p, const float* bias, float* outG,
                                                float* s, float* q, int nslice){
  int t = threadIdx.x;
  int r0 = blockIdx.x*8;
  float bval = bias[t];
  float ls = 0.f, lq = 0.f;
  for (int rr = 0; rr < 8; ++rr){
    int r = r0+rr;
    float acc = bval;
    for (int sl = 0; sl < nslice; ++sl) acc += p.part[((size_t)sl*NROW + r)*DH + t];
    outG[(size_t)r*DH + t] = acc;
    ls += acc; lq += acc*acc;
  }
  atomicAdd(&s[t], ls); atomicAdd(&q[t], lq);
}

// ---- FC mid partials: BN(prev)+relu staged, K split 2x128 (round-6 proven) ----
__global__ __launch_bounds__(256) void k_fcmid(P p, const float* in, const float* ps,
    const float* pq, const float* gamma, const float* beta, const float* W){
  __shared__ float row[FM_ROWS*FM_KS];
  int t = threadIdx.x;
  int r0 = blockIdx.x*FM_ROWS;
  int k0 = blockIdx.y*FM_KS;
  const float invM = 1.0f/(float)NROW;
  #pragma unroll
  for (int i = 0; i < 2; ++i){
    int idx = t + i*256;          // 0..511
    int rr = idx >> 7, kk = idx & 127;
    int c = k0 + kk;
    float mu = ps[c]*invM;
    float var = pq[c]*invM - mu*mu;
    float rs = rsqrtf(var + BN_EPS);
    float v = in[(size_t)(r0+rr)*DH + c];
    row[rr*FM_KS + kk] = fmaxf((v-mu)*rs*gamma[c] + beta[c], 0.0f);
  }
  __syncthreads();
  float acc[FM_ROWS] = {0.f,0.f,0.f,0.f};
  #pragma unroll 4
  for (int kk = 0; kk < FM_KS; ++kk){
    float w = W[(size_t)(k0+kk)*DH + t];
    #pragma unroll
    for (int rr = 0; rr < FM_ROWS; ++rr) acc[rr] += row[rr*FM_KS + kk]*w;
  }
  for (int rr = 0; rr < FM_ROWS; ++rr)
    p.part[((size_t)blockIdx.y*NROW + r0+rr)*DH + t] = acc[rr];
}

__global__ __launch_bounds__(256) void k_final(P p){
  int t = threadIdx.x;
  int wave = t>>6, lane = t&63;
  int r = blockIdx.x*4 + wave;
  const float invM = 1.0f/(float)NROW;
  float sum = 0.f;
  #pragma unroll
  for (int j = 0; j < 4; ++j){
    int c = lane + 64*j;
    float mu = p.s3[c]*invM;
    float var = p.q3[c]*invM - mu*mu;
    float rs = rsqrtf(var+BN_EPS);
    float v = p.G3[(size_t)r*DH + c];
    v = fmaxf((v-mu)*rs*p.gbC[c] + p.bbC[c], 0.0f);
    sum += v*p.W4[c];
  }
  #pragma unroll
  for (int off = 32; off > 0; off >>= 1) sum += __shfl_down(sum, off, 64);
  if (lane == 0){
    float z = sum + p.b4[0];
    p.out[r] = 1.0f/(1.0f + expf(-z));
  }
}

extern "C" void kernel_launch(void* const* d_in, const int* in_sizes, int n_in,
                              void* d_out, int out_size, void* d_ws, size_t ws_size,
                              hipStream_t stream) {
  P p;
  p.x     = (const float*)d_in[0];
  p.pg    = (const float*)d_in[1];
  p.neigh = (const float*)d_in[2];
  p.Winit = (const float*)d_in[3];
  p.binit = (const float*)d_in[4];
  p.g1    = (const float*)d_in[5];
  p.be1   = (const float*)d_in[6];
  p.g2    = (const float*)d_in[7];
  p.be2   = (const float*)d_in[8];
  p.Wfc   = (const float*)d_in[9];
  p.bfc   = (const float*)d_in[10];
  p.W2    = (const float*)d_in[11];
  p.b2    = (const float*)d_in[12];
  p.W3    = (const float*)d_in[13];
  p.b3    = (const float*)d_in[14];
  p.W4    = (const float*)d_in[15];
  p.b4    = (const float*)d_in[16];
  p.gbA   = (const float*)d_in[17];
  p.bbA   = (const float*)d_in[18];
  p.gbB   = (const float*)d_in[19];
  p.bbB   = (const float*)d_in[20];
  p.gbC   = (const float*)d_in[21];
  p.bbC   = (const float*)d_in[22];
  p.esrc  = (const int*)d_in[23];
  p.edst  = (const int*)d_in[24];
  p.n2g   = (const int*)d_in[25];
  p.out   = (float*)d_out;

  float* ws = (float*)d_ws;
  size_t off = 0;
  p.hb0 = (unsigned short*)(ws + off); off += (size_t)N_NODES*D/2;
  p.hb1 = (unsigned short*)(ws + off); off += (size_t)N_NODES*D/2;
  p.hb2 = (unsigned short*)(ws + off); off += (size_t)N_NODES*D/2;
  p.zbuf  = ws + off;                 // zero region start
  p.csum1 = ws + off; off += 512;
  p.csq1  = ws + off; off += 512;
  p.csum2 = ws + off; off += 512;
  p.csq2  = ws + off; off += 512;
  p.s1    = ws + off; off += 256;
  p.q1    = ws + off; off += 256;
  p.s2    = ws + off; off += 256;
  p.q2    = ws + off; off += 256;
  p.s3    = ws + off; off += 256;
  p.q3    = ws + off; off += 256;
  p.qemb  = ws + off; off += (size_t)B*D;   // end zero region (ZCOUNT floats total)
  p.G1   = ws + off; off += (size_t)NROW*DH;
  p.G2   = ws + off; off += (size_t)NROW*DH;
  p.G3   = ws + off; off += (size_t)NROW*DH;
  p.part = ws + off; off += (size_t)F1_NS*NROW*DH;
  p.degi     = (int*)(ws + off); off += N_NODES;
  p.rowstart = (int*)(ws + off); off += N_NODES + 1;
  p.cursor   = (int*)(ws + off); off += N_NODES;
  p.csr      = (int*)(ws + off); off += N_EDGES;
  p.gstart   = (int*)(ws + off); off += B + 1;

  k_setup<<<64, 256, 0, stream>>>(p);
  k_deg_init<<<DEG_BLOCKS + IM_UNITS, 256, 0, stream>>>(p);
  k_scan<<<1, 256, 0, stream>>>(p);
  k_fill<<<(N_EDGES+255)/256, 256, 0, stream>>>(p);
  k_g1<<<GBLOCKS, 256, 0, stream>>>(p);
  k_g2<<<GBLOCKS, 256, 0, stream>>>(p);
  k_readout<<<512, 256, 0, stream>>>(p);
  k_fc1<<<480, 256, 0, stream>>>(p);
  k_reduce<<<NROW/8, 256, 0, stream>>>(p, p.bfc, p.G1, p.s1, p.q1, F1_NS);
  k_fcmid<<<dim3(NROW/FM_ROWS, FM_NS), 256, 0, stream>>>(p, p.G1, p.s1, p.q1, p.gbA, p.bbA, p.W2);
  k_reduce<<<NROW/8, 256, 0, stream>>>(p, p.b2, p.G2, p.s2, p.q2, FM_NS);
  k_fcmid<<<dim3(NROW/FM_ROWS, FM_NS), 256, 0, stream>>>(p, p.G2, p.s2, p.q2, p.gbB, p.bbB, p.W3);
  k_reduce<<<NROW/8, 256, 0, stream>>>(p, p.b3, p.G3, p.s3, p.q3, FM_NS);
  k_final<<<NROW/4, 256, 0, stream>>>(p);
}